// Round 1
// baseline (694.883 us; speedup 1.0000x reference)
//
#include <hip/hip_runtime.h>

#define R_ 512
#define D_ 1024
#define G_ 16
#define NTHREADS 256

// -------------------- kernel 1: QKV projections + box params --------------------
__global__ __launch_bounds__(256) void proj_kernel(
    const float* __restrict__ feat, const float* __restrict__ boxes,
    const float* __restrict__ Wq, const float* __restrict__ bq,
    const float* __restrict__ Wk, const float* __restrict__ bk,
    const float* __restrict__ Wv, const float* __restrict__ bv,
    float* __restrict__ qbuf, float* __restrict__ kbuf, float* __restrict__ vbuf,
    float* __restrict__ bp)
{
    __shared__ float s_f[8][D_];
    const int t = threadIdx.x;
    const long row0 = (long)blockIdx.x * 8;

    const float4* f4 = (const float4*)(feat + row0 * D_);
    float4* s4 = (float4*)&s_f[0][0];
    #pragma unroll
    for (int i = 0; i < (8 * D_ / 4) / NTHREADS; i++)
        s4[t + i * NTHREADS] = f4[t + i * NTHREADS];

    if (t < 8) {
        long r = row0 + t;
        float ymin = boxes[r*4+0], xmin = boxes[r*4+1];
        float ymax = boxes[r*4+2], xmax = boxes[r*4+3];
        float h = ymax - ymin + 1.0f, w = xmax - xmin + 1.0f;
        bp[r*6+0] = 0.5f * (ymin + ymax);
        bp[r*6+1] = 0.5f * (xmin + xmax);
        bp[r*6+2] = 1.0f / h;
        bp[r*6+3] = 1.0f / w;
        bp[r*6+4] = __logf(h);
        bp[r*6+5] = __logf(w);
    }
    __syncthreads();

    if (t < 192) {
        const int which = t >> 6, col = t & 63;
        const float* W = (which == 0) ? Wq : (which == 1) ? Wk : Wv;
        const float* B = (which == 0) ? bq : (which == 1) ? bk : bv;
        float* O       = (which == 0) ? qbuf : (which == 1) ? kbuf : vbuf;

        float acc[8] = {0,0,0,0,0,0,0,0};
        #pragma unroll 4
        for (int d = 0; d < D_; d++) {
            float wv = W[d * 64 + col];
            #pragma unroll
            for (int rr = 0; rr < 8; rr++)
                acc[rr] += s_f[rr][d] * wv;
        }
        float b = B[col];
        #pragma unroll
        for (int rr = 0; rr < 8; rr++)
            O[(row0 + rr) * 64 + col] = acc[rr] + b;
    }
}

// -------------------- kernel 2: fused relation per (n, q) row --------------------
__global__ __launch_bounds__(256) void relation_kernel(
    const float* __restrict__ feat,
    const float* __restrict__ geo_w, const float* __restrict__ geo_b,
    const float* __restrict__ qbuf, const float* __restrict__ kbuf,
    const float* __restrict__ vbuf, const float* __restrict__ bp,
    float* __restrict__ out)
{
    __shared__ float s_logits[G_][R_];   // 32 KB: logits, then exp values
    __shared__ float s_v[128 * 64];      // 32 KB v tile
    __shared__ float s_inv[G_];

    const int t = threadIdx.x;
    const int nq = blockIdx.x;
    const int n = nq >> 9;               // R_ = 512

    // query-side params (uniform addresses -> scalar loads)
    const float* qb = bp + (long)nq * 6;
    const float cyq = qb[0], cxq = qb[1], ihq = qb[2], iwq = qb[3],
                lhq = qb[4], lwq = qb[5];
    const float4* q4 = (const float4*)(qbuf + (long)nq * 64);

    const float c_invdim[8] = {1.0f, 0.4216965034f, 0.1778279410f, 0.0749894209f,
                               0.0316227766f, 0.0133352143f, 0.0056234133f, 0.0023713737f};

    // ---- phase 1: all logits ----
    for (int k = t; k < R_; k += NTHREADS) {
        const float* kb = bp + (long)(n * R_ + k) * 6;
        float cyk = kb[0], cxk = kb[1], lhk = kb[4], lwk = kb[5];
        float pos[4];
        pos[0] = __logf(fmaxf((cyq - cyk) * ihq, 1e-5f));
        pos[1] = __logf(fmaxf((cxq - cxk) * iwq, 1e-5f));
        pos[2] = lhq - lhk;
        pos[3] = lwq - lwk;

        float gw[G_];
        #pragma unroll
        for (int g = 0; g < G_; g++) gw[g] = geo_b[g];

        #pragma unroll
        for (int p = 0; p < 4; p++) {
            float pr = pos[p] * 15.91549431f;   // * 100 / (2*pi): radians -> revolutions
            #pragma unroll
            for (int f = 0; f < 8; f++) {
                float r = pr * c_invdim[f];
                r -= rintf(r);                  // reduce to [-0.5, 0.5] revolutions
                float sv = __builtin_amdgcn_sinf(r);   // sin(2*pi*r)
                float cv = __builtin_amdgcn_cosf(r);
                #pragma unroll
                for (int g = 0; g < G_; g++) {
                    gw[g] += sv * geo_w[(p*16 + f)     * G_ + g];
                    gw[g] += cv * geo_w[(p*16 + 8 + f) * G_ + g];
                }
            }
        }

        const float4* k4 = (const float4*)(kbuf + (long)(n * R_ + k) * 64);
        #pragma unroll
        for (int g = 0; g < G_; g++) {
            float4 kk = k4[g];
            float4 qq = q4[g];
            float aw = (qq.x*kk.x + qq.y*kk.y + qq.z*kk.z + qq.w*kk.w) * 0.5f;
            s_logits[g][k] = __logf(fmaxf(gw[g], 1e-6f)) + aw;
        }
    }
    __syncthreads();

    // ---- phase 2: softmax (16 groups x 16 lanes), write exp back ----
    {
        const int g2 = t >> 4, j2 = t & 15;
        float mx = -1e30f;
        for (int k = j2; k < R_; k += 16) mx = fmaxf(mx, s_logits[g2][k]);
        #pragma unroll
        for (int off = 8; off >= 1; off >>= 1) mx = fmaxf(mx, __shfl_xor(mx, off));
        float sum = 0.f;
        for (int k = j2; k < R_; k += 16) {
            float e = __expf(s_logits[g2][k] - mx);
            s_logits[g2][k] = e;
            sum += e;
        }
        #pragma unroll
        for (int off = 8; off >= 1; off >>= 1) sum += __shfl_xor(sum, off);
        if (j2 == 0) s_inv[g2] = 1.0f / sum;
    }

    // ---- phase 3: out[g][d] = (sum_k e[g][k] * v[k][d]) * inv[g] + feat ----
    const int d = t & 63, wv = t >> 6;
    float acc0 = 0.f, acc1 = 0.f, acc2 = 0.f, acc3 = 0.f;
    for (int kt = 0; kt < R_; kt += 128) {
        __syncthreads();   // also covers phase2 -> phase3 on first iteration
        const float4* vsrc = (const float4*)(vbuf + (long)(n * R_ + kt) * 64);
        #pragma unroll
        for (int i = 0; i < (128 * 64 / 4) / NTHREADS; i++)
            ((float4*)s_v)[t + i * NTHREADS] = vsrc[t + i * NTHREADS];
        __syncthreads();
        #pragma unroll 4
        for (int kk = 0; kk < 128; kk++) {
            float vv = s_v[kk * 64 + d];
            int k = kt + kk;
            acc0 += s_logits[wv     ][k] * vv;
            acc1 += s_logits[wv + 4 ][k] * vv;
            acc2 += s_logits[wv + 8 ][k] * vv;
            acc3 += s_logits[wv + 12][k] * vv;
        }
    }

    const float* frow = feat + (long)nq * D_;
    float* orow = out + (long)nq * D_;
    orow[(wv     ) * 64 + d] = frow[(wv     ) * 64 + d] + acc0 * s_inv[wv     ];
    orow[(wv + 4 ) * 64 + d] = frow[(wv + 4 ) * 64 + d] + acc1 * s_inv[wv + 4 ];
    orow[(wv + 8 ) * 64 + d] = frow[(wv + 8 ) * 64 + d] + acc2 * s_inv[wv + 8 ];
    orow[(wv + 12) * 64 + d] = frow[(wv + 12) * 64 + d] + acc3 * s_inv[wv + 12];
}

extern "C" void kernel_launch(void* const* d_in, const int* in_sizes, int n_in,
                              void* d_out, int out_size, void* d_ws, size_t ws_size,
                              hipStream_t stream) {
    const float* feat  = (const float*)d_in[0];
    const float* boxes = (const float*)d_in[1];
    const float* geo_w = (const float*)d_in[2];
    const float* geo_b = (const float*)d_in[3];
    const float* Wq    = (const float*)d_in[4];
    const float* bq    = (const float*)d_in[5];
    const float* Wk    = (const float*)d_in[6];
    const float* bk    = (const float*)d_in[7];
    const float* Wv    = (const float*)d_in[8];
    const float* bv    = (const float*)d_in[9];
    float* out = (float*)d_out;

    const int N  = in_sizes[0] / (R_ * D_);
    const int NR = N * R_;

    float* qbuf = (float*)d_ws;
    float* kbuf = qbuf + (long)NR * 64;
    float* vbuf = kbuf + (long)NR * 64;
    float* bp   = vbuf + (long)NR * 64;

    proj_kernel<<<dim3(NR / 8), dim3(NTHREADS), 0, stream>>>(
        feat, boxes, Wq, bq, Wk, bk, Wv, bv, qbuf, kbuf, vbuf, bp);
    relation_kernel<<<dim3(NR), dim3(NTHREADS), 0, stream>>>(
        feat, geo_w, geo_b, qbuf, kbuf, vbuf, bp, out);
}

// Round 2
// 113.446 us; speedup vs baseline: 6.1252x; 6.1252x over previous
//
#include <hip/hip_runtime.h>
#include <stdint.h>

#define R_ 512
#define D_ 1024
#define G_ 16
#define NT 256

typedef __attribute__((ext_vector_type(8))) short short8;
typedef __attribute__((ext_vector_type(4))) float floatx4;

__device__ __forceinline__ unsigned pk2bf(float a, float b) {
    unsigned ua = __builtin_bit_cast(unsigned, a) + 0x8000u;
    unsigned ub = __builtin_bit_cast(unsigned, b) + 0x8000u;
    return (ub & 0xFFFF0000u) | (ua >> 16);
}
__device__ __forceinline__ unsigned short f2bf(float a) {
    return (unsigned short)((__builtin_bit_cast(unsigned, a) + 0x8000u) >> 16);
}

// -------------------- kernel 1: QKV projections + box params --------------------
__global__ __launch_bounds__(256) void proj_kernel(
    const float* __restrict__ feat, const float* __restrict__ boxes,
    const float* __restrict__ Wq, const float* __restrict__ bq,
    const float* __restrict__ Wk, const float* __restrict__ bk,
    const float* __restrict__ Wv, const float* __restrict__ bv,
    float* __restrict__ qbuf, unsigned short* __restrict__ kb16,
    unsigned short* __restrict__ vT16,
    float4* __restrict__ bp4, float2* __restrict__ bp2)
{
    __shared__ float s_f[8][D_];
    const int t = threadIdx.x;
    const long row0 = (long)blockIdx.x * 8;

    const float4* f4 = (const float4*)(feat + row0 * D_);
    float4* s4 = (float4*)&s_f[0][0];
    #pragma unroll
    for (int i = 0; i < (8 * D_ / 4) / NT; i++)
        s4[t + i * NT] = f4[t + i * NT];

    if (t < 8) {
        long r = row0 + t;
        float ymin = boxes[r*4+0], xmin = boxes[r*4+1];
        float ymax = boxes[r*4+2], xmax = boxes[r*4+3];
        float h = ymax - ymin + 1.0f, w = xmax - xmin + 1.0f;
        bp4[r] = make_float4(0.5f * (ymin + ymax), 0.5f * (xmin + xmax),
                             __logf(h), __logf(w));
        bp2[r] = make_float2(1.0f / h, 1.0f / w);
    }
    __syncthreads();

    if (t < 192) {
        const int which = t >> 6, col = t & 63;
        const float* W = (which == 0) ? Wq : (which == 1) ? Wk : Wv;
        const float* B = (which == 0) ? bq : (which == 1) ? bk : bv;

        float acc[8] = {0,0,0,0,0,0,0,0};
        #pragma unroll 4
        for (int d = 0; d < D_; d++) {
            float wv = W[d * 64 + col];
            #pragma unroll
            for (int rr = 0; rr < 8; rr++)
                acc[rr] += s_f[rr][d] * wv;
        }
        float b = B[col];
        #pragma unroll
        for (int rr = 0; rr < 8; rr++) {
            long r = row0 + rr;
            float val = acc[rr] + b;
            if (which == 0)      qbuf[r * 64 + col] = val;
            else if (which == 1) kb16[r * 64 + col] = f2bf(val);
            else                 vT16[((size_t)((r >> 9) * 64 + col)) * 512 + (r & 511)] = f2bf(val);
        }
    }
}

// -------------------- kernel 2: fused relation per (n, q) row --------------------
__global__ __launch_bounds__(256) void relation_kernel(
    const float* __restrict__ feat,
    const float* __restrict__ geo_w, const float* __restrict__ geo_b,
    const float* __restrict__ qbuf, const unsigned short* __restrict__ kb16,
    const unsigned short* __restrict__ vT16,
    const float4* __restrict__ bp4, const float2* __restrict__ bp2,
    float* __restrict__ out)
{
    // per-wave emb tile, double-buffered: rows padded to 72 halfwords (144 B, 16B-aligned)
    __shared__ __align__(16) unsigned short s_emb[4][2][16 * 72];
    __shared__ __align__(16) unsigned short s_p[16][520];   // exp weights bf16, padded
    __shared__ float s_redm[4][16];
    __shared__ float s_reds[4][16];

    const int t = threadIdx.x;
    const int l = t & 63;
    const int w = t >> 6;
    const int g = l & 15;
    const int quad = l >> 4;
    const int nq = blockIdx.x;
    const int n = nq >> 9;

    const float4 qb = bp4[nq];      // cy, cx, log h, log w (query side)
    const float2 qi = bp2[nq];      // 1/h, 1/w (query side)
    const float gbias = geo_b[g];

    // B-fragments: geo_w [64e x 16g] and block-diag(0.5*q) [64e x 16g], bf16
    short8 bgeo[2], bqf[2];
    #pragma unroll
    for (int h = 0; h < 2; h++) {
        #pragma unroll
        for (int j = 0; j < 8; j++) {
            int e = h * 32 + quad * 8 + j;
            bgeo[h][j] = (short)f2bf(geo_w[e * G_ + g]);
            bqf[h][j]  = (short)(((e >> 2) == g) ? f2bf(0.5f * qbuf[(size_t)nq * 64 + e]) : 0);
        }
    }

    // angle constants: 100/(2*pi) * 1000^(-f/8)  (revolutions)
    const float C8[8] = {
        15.91549431f,
        15.91549431f * 0.4216965034f,
        15.91549431f * 0.1778279410f,
        15.91549431f * 0.0749894209f,
        15.91549431f * 0.0316227766f,
        15.91549431f * 0.0133352143f,
        15.91549431f * 0.0056234133f,
        15.91549431f * 0.0023713737f };

    float logit[8][4];
    const unsigned short* krow_base = kb16 + ((size_t)(n * R_ + w * 128)) * 64;

    #pragma unroll
    for (int ti = 0; ti < 8; ti++) {
        unsigned short* ebuf = &s_emb[w][ti & 1][0];
        // ---- trig: lane computes (row = g, p = quad): 8 sin + 8 cos, pack bf16 ----
        {
            int krow = n * R_ + w * 128 + ti * 16 + g;
            float4 kb = bp4[krow];
            float a  = (quad == 0) ? (qb.x - kb.x) * qi.x : (qb.y - kb.y) * qi.y;
            float lg = __logf(fmaxf(a, 1e-5f));
            float df = (quad == 2) ? (qb.z - kb.z) : (qb.w - kb.w);
            float pos = (quad < 2) ? lg : df;

            uint4 sp, cp;
            float r0, r1;
            r0 = pos * C8[0]; r0 -= rintf(r0); r1 = pos * C8[1]; r1 -= rintf(r1);
            sp.x = pk2bf(__builtin_amdgcn_sinf(r0), __builtin_amdgcn_sinf(r1));
            cp.x = pk2bf(__builtin_amdgcn_cosf(r0), __builtin_amdgcn_cosf(r1));
            r0 = pos * C8[2]; r0 -= rintf(r0); r1 = pos * C8[3]; r1 -= rintf(r1);
            sp.y = pk2bf(__builtin_amdgcn_sinf(r0), __builtin_amdgcn_sinf(r1));
            cp.y = pk2bf(__builtin_amdgcn_cosf(r0), __builtin_amdgcn_cosf(r1));
            r0 = pos * C8[4]; r0 -= rintf(r0); r1 = pos * C8[5]; r1 -= rintf(r1);
            sp.z = pk2bf(__builtin_amdgcn_sinf(r0), __builtin_amdgcn_sinf(r1));
            cp.z = pk2bf(__builtin_amdgcn_cosf(r0), __builtin_amdgcn_cosf(r1));
            r0 = pos * C8[6]; r0 -= rintf(r0); r1 = pos * C8[7]; r1 -= rintf(r1);
            sp.w = pk2bf(__builtin_amdgcn_sinf(r0), __builtin_amdgcn_sinf(r1));
            cp.w = pk2bf(__builtin_amdgcn_cosf(r0), __builtin_amdgcn_cosf(r1));

            // e = p*16 + f (sin f=0..7), p*16+8+f (cos): bytes row*144 + p*32 (+16)
            *(uint4*)(ebuf + g * 72 + quad * 16)     = sp;
            *(uint4*)(ebuf + g * 72 + quad * 16 + 8) = cp;
        }

        // ---- fragments: A_emb from LDS, A_k from global (bf16 16B chunks) ----
        short8 ae0 = *(const short8*)(ebuf + g * 72 + quad * 8);
        short8 ae1 = *(const short8*)(ebuf + g * 72 + 32 + quad * 8);
        const unsigned short* kr = krow_base + ((size_t)(ti * 16 + g)) * 64;
        short8 ak0 = *(const short8*)(kr + quad * 8);
        short8 ak1 = *(const short8*)(kr + 32 + quad * 8);

        floatx4 accg = {0.f, 0.f, 0.f, 0.f};
        floatx4 acck = {0.f, 0.f, 0.f, 0.f};
        accg = __builtin_amdgcn_mfma_f32_16x16x32_bf16(ae0, bgeo[0], accg, 0, 0, 0);
        accg = __builtin_amdgcn_mfma_f32_16x16x32_bf16(ae1, bgeo[1], accg, 0, 0, 0);
        acck = __builtin_amdgcn_mfma_f32_16x16x32_bf16(ak0, bqf[0], acck, 0, 0, 0);
        acck = __builtin_amdgcn_mfma_f32_16x16x32_bf16(ak1, bqf[1], acck, 0, 0, 0);

        #pragma unroll
        for (int r = 0; r < 4; r++)
            logit[ti][r] = __logf(fmaxf(accg[r] + gbias, 1e-6f)) + acck[r];
    }

    // ---- softmax over k (per g): lane holds 32 logits for its g ----
    float mx = -3.0e38f;
    #pragma unroll
    for (int ti = 0; ti < 8; ti++)
        #pragma unroll
        for (int r = 0; r < 4; r++)
            mx = fmaxf(mx, logit[ti][r]);
    mx = fmaxf(mx, __shfl_xor(mx, 16));
    mx = fmaxf(mx, __shfl_xor(mx, 32));
    if (l < 16) s_redm[w][l] = mx;
    __syncthreads();
    float mg = fmaxf(fmaxf(s_redm[0][g], s_redm[1][g]),
                     fmaxf(s_redm[2][g], s_redm[3][g]));

    float sum = 0.f;
    #pragma unroll
    for (int ti = 0; ti < 8; ti++) {
        float e0 = __expf(logit[ti][0] - mg);
        float e1 = __expf(logit[ti][1] - mg);
        float e2 = __expf(logit[ti][2] - mg);
        float e3 = __expf(logit[ti][3] - mg);
        sum += (e0 + e1) + (e2 + e3);
        int k0 = w * 128 + ti * 16 + quad * 4;
        *(unsigned*)&s_p[g][k0]     = pk2bf(e0, e1);
        *(unsigned*)&s_p[g][k0 + 2] = pk2bf(e2, e3);
    }
    sum += __shfl_xor(sum, 16);
    sum += __shfl_xor(sum, 32);
    if (l < 16) s_reds[w][l] = sum;
    __syncthreads();

    // ---- PV: out[g][d] = sum_k p[g][k] * v[k][d]; wave w owns d-tile w*16..+16 ----
    floatx4 accp = {0.f, 0.f, 0.f, 0.f};
    const unsigned short* vrow = vT16 + ((size_t)(n * 64 + w * 16 + g)) * 512;
    #pragma unroll
    for (int ks = 0; ks < 16; ks++) {
        short8 ap  = *(const short8*)(&s_p[g][ks * 32 + quad * 8]);
        short8 bv8 = *(const short8*)(vrow + ks * 32 + quad * 8);
        accp = __builtin_amdgcn_mfma_f32_16x16x32_bf16(ap, bv8, accp, 0, 0, 0);
    }

    #pragma unroll
    for (int r = 0; r < 4; r++) {
        int gg = quad * 4 + r;
        float s = (s_reds[0][gg] + s_reds[1][gg]) + (s_reds[2][gg] + s_reds[3][gg]);
        size_t o = (size_t)nq * D_ + (size_t)gg * 64 + w * 16 + g;
        out[o] = feat[o] + accp[r] / s;
    }
}

extern "C" void kernel_launch(void* const* d_in, const int* in_sizes, int n_in,
                              void* d_out, int out_size, void* d_ws, size_t ws_size,
                              hipStream_t stream) {
    const float* feat  = (const float*)d_in[0];
    const float* boxes = (const float*)d_in[1];
    const float* geo_w = (const float*)d_in[2];
    const float* geo_b = (const float*)d_in[3];
    const float* Wq    = (const float*)d_in[4];
    const float* bq    = (const float*)d_in[5];
    const float* Wk    = (const float*)d_in[6];
    const float* bk    = (const float*)d_in[7];
    const float* Wv    = (const float*)d_in[8];
    const float* bv    = (const float*)d_in[9];
    float* out = (float*)d_out;

    const int N  = in_sizes[0] / (R_ * D_);
    const int NR = N * R_;

    float* qbuf = (float*)d_ws;                                  // NR*64 f32
    float4* bp4 = (float4*)(qbuf + (size_t)NR * 64);             // NR float4
    float2* bp2 = (float2*)(bp4 + NR);                           // NR float2
    unsigned short* kb16 = (unsigned short*)(bp2 + NR);          // NR*64 bf16
    unsigned short* vT16 = kb16 + (size_t)NR * 64;               // NR*64 bf16 (transposed)

    proj_kernel<<<dim3(NR / 8), dim3(NT), 0, stream>>>(
        feat, boxes, Wq, bq, Wk, bk, Wv, bv, qbuf, kb16, vT16, bp4, bp2);
    relation_kernel<<<dim3(NR), dim3(NT), 0, stream>>>(
        feat, geo_w, geo_b, qbuf, kb16, vT16, bp4, bp2, out);
}

// Round 3
// 90.960 us; speedup vs baseline: 7.6395x; 1.2472x over previous
//
#include <hip/hip_runtime.h>
#include <stdint.h>

#define R_ 512
#define D_ 1024
#define G_ 16
#define NT 256

typedef __attribute__((ext_vector_type(8))) short short8;
typedef __attribute__((ext_vector_type(4))) float floatx4;

__device__ __forceinline__ unsigned pk2bf(float a, float b) {
    unsigned ua = __builtin_bit_cast(unsigned, a) + 0x8000u;
    unsigned ub = __builtin_bit_cast(unsigned, b) + 0x8000u;
    return (ub & 0xFFFF0000u) | (ua >> 16);
}
__device__ __forceinline__ unsigned short f2bf(float a) {
    return (unsigned short)((__builtin_bit_cast(unsigned, a) + 0x8000u) >> 16);
}

// ---------- kernel 0: W transpose->bf16  +  box params ----------
__global__ __launch_bounds__(256) void prep_kernel(
    const float* __restrict__ Wq, const float* __restrict__ Wk,
    const float* __restrict__ Wv, const float* __restrict__ boxes,
    unsigned short* __restrict__ WTb, float4* __restrict__ bp4,
    float2* __restrict__ bp2, int NR)
{
    const int b = blockIdx.x, t = threadIdx.x;
    if (b < 48) {
        __shared__ float s[64][65];
        const int mat = b >> 4, rblk = b & 15;
        const float* Wsrc = (mat == 0) ? Wq : (mat == 1) ? Wk : Wv;
        const int d0 = rblk * 64;
        #pragma unroll
        for (int i = 0; i < 16; i++) {
            int e = t + i * 256;
            s[e >> 6][e & 63] = Wsrc[(size_t)(d0 + (e >> 6)) * 64 + (e & 63)];
        }
        __syncthreads();
        #pragma unroll
        for (int i = 0; i < 16; i++) {
            int e = t + i * 256;
            int c = e >> 6, r = e & 63;
            WTb[(size_t)(mat * 64 + c) * 1024 + d0 + r] = f2bf(s[r][c]);
        }
    } else {
        int r = (b - 48) * 256 + t;
        if (r < NR) {
            float ymin = boxes[r*4+0], xmin = boxes[r*4+1];
            float ymax = boxes[r*4+2], xmax = boxes[r*4+3];
            float h = ymax - ymin + 1.0f, w = xmax - xmin + 1.0f;
            bp4[r] = make_float4(0.5f * (ymin + ymax), 0.5f * (xmin + xmax),
                                 __logf(h), __logf(w));
            bp2[r] = make_float2(1.0f / h, 1.0f / w);
        }
    }
}

// ---------- kernel 1: QKV projection via MFMA ----------
__global__ __launch_bounds__(256) void proj_kernel(
    const float* __restrict__ feat, const unsigned short* __restrict__ WTb,
    const float* __restrict__ bq, const float* __restrict__ bk,
    const float* __restrict__ bv,
    float* __restrict__ qbuf, unsigned short* __restrict__ kb16,
    unsigned short* __restrict__ vT16)
{
    __shared__ __align__(16) unsigned short s_A[16][1032];  // 16 rows, padded pitch

    const int t = threadIdx.x, l = t & 63, w = t >> 6;
    const long row0 = (long)blockIdx.x * 16;

    // stage 16 feat rows -> bf16 LDS (coalesced float4 reads)
    const float4* f4 = (const float4*)(feat + row0 * D_);
    #pragma unroll
    for (int i = 0; i < 16; i++) {
        int e = t + i * 256;              // float4 index over 16*256
        int row = e >> 8, c4 = e & 255;
        float4 v = f4[e];
        uint2 pk;
        pk.x = pk2bf(v.x, v.y);
        pk.y = pk2bf(v.z, v.w);
        *(uint2*)&s_A[row][c4 * 4] = pk;
    }
    __syncthreads();

    const int lc = l & 15, q = l >> 4;
    floatx4 acc[3] = {{0,0,0,0},{0,0,0,0},{0,0,0,0}};
    const unsigned short* bptr[3];
    #pragma unroll
    for (int ct = 0; ct < 3; ct++) {
        int gcol = w * 48 + ct * 16 + lc;
        bptr[ct] = WTb + (size_t)gcol * 1024 + q * 8;
    }

    #pragma unroll 8
    for (int k0 = 0; k0 < 1024; k0 += 32) {
        short8 a = *(const short8*)&s_A[lc][k0 + q * 8];
        #pragma unroll
        for (int ct = 0; ct < 3; ct++) {
            short8 bb = *(const short8*)(bptr[ct] + k0);
            acc[ct] = __builtin_amdgcn_mfma_f32_16x16x32_bf16(a, bb, acc[ct], 0, 0, 0);
        }
    }

    #pragma unroll
    for (int ct = 0; ct < 3; ct++) {
        int gbase = w * 48 + ct * 16;
        int mat = gbase >> 6;
        int mcol = (gbase & 63) + lc;
        const float* B = (mat == 0) ? bq : (mat == 1) ? bk : bv;
        float bias = B[mcol];
        #pragma unroll
        for (int r = 0; r < 4; r++) {
            int row = q * 4 + r;
            long gr = row0 + row;
            float val = acc[ct][r] + bias;
            if (mat == 0)      qbuf[gr * 64 + mcol] = val;
            else if (mat == 1) kb16[gr * 64 + mcol] = f2bf(val);
            else               vT16[((size_t)((gr >> 9) * 64 + mcol)) * 512 + (gr & 511)] = f2bf(val);
        }
    }
}

// ---------- kernel 2: fused relation per (n, q) row ----------
__global__ __launch_bounds__(256) void relation_kernel(
    const float* __restrict__ feat,
    const float* __restrict__ geo_w, const float* __restrict__ geo_b,
    const float* __restrict__ qbuf, const unsigned short* __restrict__ kb16,
    const unsigned short* __restrict__ vT16,
    const float4* __restrict__ bp4, const float2* __restrict__ bp2,
    float* __restrict__ out)
{
    __shared__ __align__(16) unsigned short s_emb[4][2][16 * 72];
    __shared__ __align__(16) unsigned short s_p[16][520];
    __shared__ float s_redm[4][16];
    __shared__ float s_reds[4][16];

    const int t = threadIdx.x;
    const int l = t & 63;
    const int w = t >> 6;
    const int g = l & 15;
    const int quad = l >> 4;
    const int nq = blockIdx.x;
    const int n = nq >> 9;

    const float4 qb = bp4[nq];
    const float2 qi = bp2[nq];
    const float gbias = geo_b[g];

    short8 bgeo[2], bqf[2];
    #pragma unroll
    for (int h = 0; h < 2; h++) {
        #pragma unroll
        for (int j = 0; j < 8; j++) {
            int e = h * 32 + quad * 8 + j;
            bgeo[h][j] = (short)f2bf(geo_w[e * G_ + g]);
            bqf[h][j]  = (short)(((e >> 2) == g) ? f2bf(0.5f * qbuf[(size_t)nq * 64 + e]) : 0);
        }
    }

    const float C8[8] = {
        15.91549431f,
        15.91549431f * 0.4216965034f,
        15.91549431f * 0.1778279410f,
        15.91549431f * 0.0749894209f,
        15.91549431f * 0.0316227766f,
        15.91549431f * 0.0133352143f,
        15.91549431f * 0.0056234133f,
        15.91549431f * 0.0023713737f };

    float logit[8][4];
    const unsigned short* krow_base = kb16 + ((size_t)(n * R_ + w * 128)) * 64;

    #pragma unroll
    for (int ti = 0; ti < 8; ti++) {
        unsigned short* ebuf = &s_emb[w][ti & 1][0];
        {
            int krow = n * R_ + w * 128 + ti * 16 + g;
            float4 kb = bp4[krow];
            float a  = (quad == 0) ? (qb.x - kb.x) * qi.x : (qb.y - kb.y) * qi.y;
            float lg = __logf(fmaxf(a, 1e-5f));
            float df = (quad == 2) ? (qb.z - kb.z) : (qb.w - kb.w);
            float pos = (quad < 2) ? lg : df;

            uint4 sp, cp;
            float r0, r1;
            r0 = pos * C8[0]; r0 -= rintf(r0); r1 = pos * C8[1]; r1 -= rintf(r1);
            sp.x = pk2bf(__builtin_amdgcn_sinf(r0), __builtin_amdgcn_sinf(r1));
            cp.x = pk2bf(__builtin_amdgcn_cosf(r0), __builtin_amdgcn_cosf(r1));
            r0 = pos * C8[2]; r0 -= rintf(r0); r1 = pos * C8[3]; r1 -= rintf(r1);
            sp.y = pk2bf(__builtin_amdgcn_sinf(r0), __builtin_amdgcn_sinf(r1));
            cp.y = pk2bf(__builtin_amdgcn_cosf(r0), __builtin_amdgcn_cosf(r1));
            r0 = pos * C8[4]; r0 -= rintf(r0); r1 = pos * C8[5]; r1 -= rintf(r1);
            sp.z = pk2bf(__builtin_amdgcn_sinf(r0), __builtin_amdgcn_sinf(r1));
            cp.z = pk2bf(__builtin_amdgcn_cosf(r0), __builtin_amdgcn_cosf(r1));
            r0 = pos * C8[6]; r0 -= rintf(r0); r1 = pos * C8[7]; r1 -= rintf(r1);
            sp.w = pk2bf(__builtin_amdgcn_sinf(r0), __builtin_amdgcn_sinf(r1));
            cp.w = pk2bf(__builtin_amdgcn_cosf(r0), __builtin_amdgcn_cosf(r1));

            *(uint4*)(ebuf + g * 72 + quad * 16)     = sp;
            *(uint4*)(ebuf + g * 72 + quad * 16 + 8) = cp;
        }

        short8 ae0 = *(const short8*)(ebuf + g * 72 + quad * 8);
        short8 ae1 = *(const short8*)(ebuf + g * 72 + 32 + quad * 8);
        const unsigned short* kr = krow_base + ((size_t)(ti * 16 + g)) * 64;
        short8 ak0 = *(const short8*)(kr + quad * 8);
        short8 ak1 = *(const short8*)(kr + 32 + quad * 8);

        floatx4 accg = {0.f, 0.f, 0.f, 0.f};
        floatx4 acck = {0.f, 0.f, 0.f, 0.f};
        accg = __builtin_amdgcn_mfma_f32_16x16x32_bf16(ae0, bgeo[0], accg, 0, 0, 0);
        accg = __builtin_amdgcn_mfma_f32_16x16x32_bf16(ae1, bgeo[1], accg, 0, 0, 0);
        acck = __builtin_amdgcn_mfma_f32_16x16x32_bf16(ak0, bqf[0], acck, 0, 0, 0);
        acck = __builtin_amdgcn_mfma_f32_16x16x32_bf16(ak1, bqf[1], acck, 0, 0, 0);

        #pragma unroll
        for (int r = 0; r < 4; r++)
            logit[ti][r] = __logf(fmaxf(accg[r] + gbias, 1e-6f)) + acck[r];
    }

    float mx = -3.0e38f;
    #pragma unroll
    for (int ti = 0; ti < 8; ti++)
        #pragma unroll
        for (int r = 0; r < 4; r++)
            mx = fmaxf(mx, logit[ti][r]);
    mx = fmaxf(mx, __shfl_xor(mx, 16));
    mx = fmaxf(mx, __shfl_xor(mx, 32));
    if (l < 16) s_redm[w][l] = mx;
    __syncthreads();
    float mg = fmaxf(fmaxf(s_redm[0][g], s_redm[1][g]),
                     fmaxf(s_redm[2][g], s_redm[3][g]));

    float sum = 0.f;
    #pragma unroll
    for (int ti = 0; ti < 8; ti++) {
        float e0 = __expf(logit[ti][0] - mg);
        float e1 = __expf(logit[ti][1] - mg);
        float e2 = __expf(logit[ti][2] - mg);
        float e3 = __expf(logit[ti][3] - mg);
        sum += (e0 + e1) + (e2 + e3);
        int k0 = w * 128 + ti * 16 + quad * 4;
        *(unsigned*)&s_p[g][k0]     = pk2bf(e0, e1);
        *(unsigned*)&s_p[g][k0 + 2] = pk2bf(e2, e3);
    }
    sum += __shfl_xor(sum, 16);
    sum += __shfl_xor(sum, 32);
    if (l < 16) s_reds[w][l] = sum;
    __syncthreads();

    floatx4 accp = {0.f, 0.f, 0.f, 0.f};
    const unsigned short* vrow = vT16 + ((size_t)(n * 64 + w * 16 + g)) * 512;
    #pragma unroll
    for (int ks = 0; ks < 16; ks++) {
        short8 ap  = *(const short8*)(&s_p[g][ks * 32 + quad * 8]);
        short8 bv8 = *(const short8*)(vrow + ks * 32 + quad * 8);
        accp = __builtin_amdgcn_mfma_f32_16x16x32_bf16(ap, bv8, accp, 0, 0, 0);
    }

    #pragma unroll
    for (int r = 0; r < 4; r++) {
        int gg = quad * 4 + r;
        float s = (s_reds[0][gg] + s_reds[1][gg]) + (s_reds[2][gg] + s_reds[3][gg]);
        size_t o = (size_t)nq * D_ + (size_t)gg * 64 + w * 16 + g;
        out[o] = feat[o] + accp[r] / s;
    }
}

extern "C" void kernel_launch(void* const* d_in, const int* in_sizes, int n_in,
                              void* d_out, int out_size, void* d_ws, size_t ws_size,
                              hipStream_t stream) {
    const float* feat  = (const float*)d_in[0];
    const float* boxes = (const float*)d_in[1];
    const float* geo_w = (const float*)d_in[2];
    const float* geo_b = (const float*)d_in[3];
    const float* Wq    = (const float*)d_in[4];
    const float* bq    = (const float*)d_in[5];
    const float* Wk    = (const float*)d_in[6];
    const float* bk    = (const float*)d_in[7];
    const float* Wv    = (const float*)d_in[8];
    const float* bv    = (const float*)d_in[9];
    float* out = (float*)d_out;

    const int N  = in_sizes[0] / (R_ * D_);
    const int NR = N * R_;

    float* qbuf = (float*)d_ws;                                  // NR*64 f32
    float4* bp4 = (float4*)(qbuf + (size_t)NR * 64);             // NR float4
    float2* bp2 = (float2*)(bp4 + NR);                           // NR float2
    unsigned short* kb16 = (unsigned short*)(bp2 + NR);          // NR*64 bf16
    unsigned short* vT16 = kb16 + (size_t)NR * 64;               // NR*64 bf16 (transposed)
    unsigned short* WTb  = vT16 + (size_t)NR * 64;               // 192*1024 bf16

    prep_kernel<<<dim3(48 + (NR + 255) / 256), dim3(NT), 0, stream>>>(
        Wq, Wk, Wv, boxes, WTb, bp4, bp2, NR);
    proj_kernel<<<dim3(NR / 16), dim3(NT), 0, stream>>>(
        feat, WTb, bq, bk, bv, qbuf, kb16, vT16);
    relation_kernel<<<dim3(NR), dim3(NT), 0, stream>>>(
        feat, geo_w, geo_b, qbuf, kb16, vT16, bp4, bp2, out);
}

// Round 4
// 87.209 us; speedup vs baseline: 7.9680x; 1.0430x over previous
//
#include <hip/hip_runtime.h>
#include <stdint.h>

#define R_ 512
#define D_ 1024
#define G_ 16
#define NT 256

typedef __attribute__((ext_vector_type(8))) short short8;
typedef __attribute__((ext_vector_type(4))) float floatx4;

__device__ __forceinline__ unsigned pk2bf(float a, float b) {
    unsigned ua = __builtin_bit_cast(unsigned, a) + 0x8000u;
    unsigned ub = __builtin_bit_cast(unsigned, b) + 0x8000u;
    return (ub & 0xFFFF0000u) | (ua >> 16);
}
__device__ __forceinline__ unsigned short f2bf(float a) {
    return (unsigned short)((__builtin_bit_cast(unsigned, a) + 0x8000u) >> 16);
}

// ---------- kernel 0: W transpose->bf16  +  box params ----------
__global__ __launch_bounds__(256) void prep_kernel(
    const float* __restrict__ Wq, const float* __restrict__ Wk,
    const float* __restrict__ Wv, const float* __restrict__ boxes,
    unsigned short* __restrict__ WTb, float4* __restrict__ bp4,
    float2* __restrict__ bp2, int NR)
{
    const int b = blockIdx.x, t = threadIdx.x;
    if (b < 48) {
        __shared__ float s[64][65];
        const int mat = b >> 4, rblk = b & 15;
        const float* Wsrc = (mat == 0) ? Wq : (mat == 1) ? Wk : Wv;
        const int d0 = rblk * 64;
        #pragma unroll
        for (int i = 0; i < 16; i++) {
            int e = t + i * 256;
            s[e >> 6][e & 63] = Wsrc[(size_t)(d0 + (e >> 6)) * 64 + (e & 63)];
        }
        __syncthreads();
        #pragma unroll
        for (int i = 0; i < 16; i++) {
            int e = t + i * 256;
            int c = e >> 6, r = e & 63;
            WTb[(size_t)(mat * 64 + c) * 1024 + d0 + r] = f2bf(s[r][c]);
        }
    } else {
        int r = (b - 48) * 256 + t;
        if (r < NR) {
            float ymin = boxes[r*4+0], xmin = boxes[r*4+1];
            float ymax = boxes[r*4+2], xmax = boxes[r*4+3];
            float h = ymax - ymin + 1.0f, w = xmax - xmin + 1.0f;
            bp4[r] = make_float4(0.5f * (ymin + ymax), 0.5f * (xmin + xmax),
                                 __logf(h), __logf(w));
            bp2[r] = make_float2(1.0f / h, 1.0f / w);
        }
    }
}

// ---------- kernel 1: QKV projection via MFMA (384 blocks) ----------
__global__ __launch_bounds__(256) void proj_kernel(
    const float* __restrict__ feat, const unsigned short* __restrict__ WTb,
    const float* __restrict__ bq, const float* __restrict__ bk,
    const float* __restrict__ bv,
    float* __restrict__ qbuf, unsigned short* __restrict__ kb16,
    unsigned short* __restrict__ vT16)
{
    __shared__ __align__(16) unsigned short s_A[16][1032];

    const int t = threadIdx.x, l = t & 63, w = t >> 6;
    const int mb = blockIdx.x / 3, ng = blockIdx.x % 3;
    const long row0 = (long)mb * 16;

    const float4* f4 = (const float4*)(feat + row0 * D_);
    #pragma unroll
    for (int i = 0; i < 16; i++) {
        int e = t + i * 256;
        int row = e >> 8, c4 = e & 255;
        float4 v = f4[e];
        uint2 pk;
        pk.x = pk2bf(v.x, v.y);
        pk.y = pk2bf(v.z, v.w);
        *(uint2*)&s_A[row][c4 * 4] = pk;
    }
    __syncthreads();

    const int lc = l & 15, q = l >> 4;
    const int gcol = (ng * 4 + w) * 16 + lc;       // 0..191
    const unsigned short* bptr = WTb + (size_t)gcol * 1024 + q * 8;

    floatx4 acc = {0.f, 0.f, 0.f, 0.f};
    #pragma unroll 8
    for (int k0 = 0; k0 < 1024; k0 += 32) {
        short8 a  = *(const short8*)&s_A[lc][k0 + q * 8];
        short8 bb = *(const short8*)(bptr + k0);
        acc = __builtin_amdgcn_mfma_f32_16x16x32_bf16(a, bb, acc, 0, 0, 0);
    }

    const int mat = gcol >> 6, mcol = gcol & 63;
    const float* B = (mat == 0) ? bq : (mat == 1) ? bk : bv;
    const float bias = B[mcol];
    #pragma unroll
    for (int r = 0; r < 4; r++) {
        long gr = row0 + q * 4 + r;
        float val = acc[r] + bias;
        if (mat == 0)      qbuf[gr * 64 + mcol] = val;
        else if (mat == 1) kb16[gr * 64 + mcol] = f2bf(val);
        else               vT16[((size_t)((gr >> 9) * 64 + mcol)) * 512 + (gr & 511)] = f2bf(val);
    }
}

// ---------- kernel 2: fused relation per (n, q) row ----------
__global__ __launch_bounds__(256) void relation_kernel(
    const float* __restrict__ feat,
    const float* __restrict__ geo_w, const float* __restrict__ geo_b,
    const float* __restrict__ qbuf, const unsigned short* __restrict__ kb16,
    const unsigned short* __restrict__ vT16,
    const float4* __restrict__ bp4, const float2* __restrict__ bp2,
    float* __restrict__ out)
{
    __shared__ __align__(16) unsigned short s_p[16][520];
    __shared__ float s_redm[4][16];
    __shared__ float s_reds[4][16];

    const int t = threadIdx.x;
    const int l = t & 63;
    const int w = t >> 6;
    const int c = l & 15;        // A-fragment row (key within 16-tile) / group col
    const int quad = l >> 4;
    const int nq = blockIdx.x;
    const int n = nq >> 9;

    const float4 qb = bp4[nq];
    const float2 qi = bp2[nq];
    const float gbias = geo_b[c];

    // B-fragments: geo_w [64e x 16g] and block-diag(0.5*q) [64e x 16g], bf16
    short8 bgeo[2], bqf[2];
    #pragma unroll
    for (int h = 0; h < 2; h++) {
        #pragma unroll
        for (int j = 0; j < 8; j++) {
            int e = h * 32 + quad * 8 + j;
            bgeo[h][j] = (short)f2bf(geo_w[e * G_ + c]);
            bqf[h][j]  = (short)(((e >> 2) == c) ? f2bf(0.5f * qbuf[(size_t)nq * 64 + e]) : 0);
        }
    }

    // C8[f] = 100/(2*pi) * 1000^(-f/8)  (angle in revolutions)
    const float C8[8] = {
        15.91549431f,
        15.91549431f * 0.4216965034f,
        15.91549431f * 0.1778279410f,
        15.91549431f * 0.0749894209f,
        15.91549431f * 0.0316227766f,
        15.91549431f * 0.0133352143f,
        15.91549431f * 0.0056234133f,
        15.91549431f * 0.0023713737f };

    // lane's fragment dims: ae0 -> e = quad*8+j  (p = quad>>1, s = quad&1)
    //                       ae1 -> e = 32+quad*8+j (p = 2+(quad>>1), s = quad&1)
    const float offs = (quad & 1) ? 0.25f : 0.0f;   // cos(2pi x) = sin(2pi(x+1/4))
    const bool qlow = (quad < 2);

    float logit[8][4];
    const unsigned short* krow_base = kb16 + ((size_t)(n * R_ + w * 128)) * 64;

    #pragma unroll
    for (int ti = 0; ti < 8; ti++) {
        int krow = n * R_ + w * 128 + ti * 16 + c;
        float4 kb = bp4[krow];
        float a     = qlow ? (qb.x - kb.x) * qi.x : (qb.y - kb.y) * qi.y;
        float pos_a = __logf(fmaxf(a, 1e-5f));
        float pos_b = qlow ? (qb.z - kb.z) : (qb.w - kb.w);

        short8 ae0, ae1;
        #pragma unroll
        for (int j = 0; j < 8; j++) {
            float r0 = pos_a * C8[j];
            r0 = r0 - rintf(r0) + offs;
            float r1 = pos_b * C8[j];
            r1 = r1 - rintf(r1) + offs;
            ae0[j] = (short)f2bf(__builtin_amdgcn_sinf(r0));
            ae1[j] = (short)f2bf(__builtin_amdgcn_sinf(r1));
        }

        const unsigned short* kr = krow_base + ((size_t)(ti * 16 + c)) * 64;
        short8 ak0 = *(const short8*)(kr + quad * 8);
        short8 ak1 = *(const short8*)(kr + 32 + quad * 8);

        floatx4 accg = {0.f, 0.f, 0.f, 0.f};
        floatx4 acck = {0.f, 0.f, 0.f, 0.f};
        accg = __builtin_amdgcn_mfma_f32_16x16x32_bf16(ae0, bgeo[0], accg, 0, 0, 0);
        accg = __builtin_amdgcn_mfma_f32_16x16x32_bf16(ae1, bgeo[1], accg, 0, 0, 0);
        acck = __builtin_amdgcn_mfma_f32_16x16x32_bf16(ak0, bqf[0], acck, 0, 0, 0);
        acck = __builtin_amdgcn_mfma_f32_16x16x32_bf16(ak1, bqf[1], acck, 0, 0, 0);

        #pragma unroll
        for (int r = 0; r < 4; r++)
            logit[ti][r] = __logf(fmaxf(accg[r] + gbias, 1e-6f)) + acck[r];
    }

    // ---- softmax over k (per group = c): lane holds 32 logits ----
    float mx = -3.0e38f;
    #pragma unroll
    for (int ti = 0; ti < 8; ti++)
        #pragma unroll
        for (int r = 0; r < 4; r++)
            mx = fmaxf(mx, logit[ti][r]);
    mx = fmaxf(mx, __shfl_xor(mx, 16));
    mx = fmaxf(mx, __shfl_xor(mx, 32));
    if (l < 16) s_redm[w][l] = mx;
    __syncthreads();
    float mg = fmaxf(fmaxf(s_redm[0][c], s_redm[1][c]),
                     fmaxf(s_redm[2][c], s_redm[3][c]));

    float sum = 0.f;
    #pragma unroll
    for (int ti = 0; ti < 8; ti++) {
        float e0 = __expf(logit[ti][0] - mg);
        float e1 = __expf(logit[ti][1] - mg);
        float e2 = __expf(logit[ti][2] - mg);
        float e3 = __expf(logit[ti][3] - mg);
        sum += (e0 + e1) + (e2 + e3);
        int k0 = w * 128 + ti * 16 + quad * 4;
        uint2 pk;
        pk.x = pk2bf(e0, e1);
        pk.y = pk2bf(e2, e3);
        *(uint2*)&s_p[c][k0] = pk;
    }
    sum += __shfl_xor(sum, 16);
    sum += __shfl_xor(sum, 32);
    if (l < 16) s_reds[w][l] = sum;
    __syncthreads();

    // ---- PV: wave w owns d-tile [w*16, w*16+16) ----
    floatx4 accp = {0.f, 0.f, 0.f, 0.f};
    const unsigned short* vrow = vT16 + ((size_t)(n * 64 + w * 16 + c)) * 512;
    #pragma unroll
    for (int ks = 0; ks < 16; ks++) {
        short8 ap  = *(const short8*)(&s_p[c][ks * 32 + quad * 8]);
        short8 bv8 = *(const short8*)(vrow + ks * 32 + quad * 8);
        accp = __builtin_amdgcn_mfma_f32_16x16x32_bf16(ap, bv8, accp, 0, 0, 0);
    }

    #pragma unroll
    for (int r = 0; r < 4; r++) {
        int gg = quad * 4 + r;
        float s = (s_reds[0][gg] + s_reds[1][gg]) + (s_reds[2][gg] + s_reds[3][gg]);
        size_t o = (size_t)nq * D_ + (size_t)gg * 64 + w * 16 + c;
        out[o] = feat[o] + accp[r] / s;
    }
}

extern "C" void kernel_launch(void* const* d_in, const int* in_sizes, int n_in,
                              void* d_out, int out_size, void* d_ws, size_t ws_size,
                              hipStream_t stream) {
    const float* feat  = (const float*)d_in[0];
    const float* boxes = (const float*)d_in[1];
    const float* geo_w = (const float*)d_in[2];
    const float* geo_b = (const float*)d_in[3];
    const float* Wq    = (const float*)d_in[4];
    const float* bq    = (const float*)d_in[5];
    const float* Wk    = (const float*)d_in[6];
    const float* bk    = (const float*)d_in[7];
    const float* Wv    = (const float*)d_in[8];
    const float* bv    = (const float*)d_in[9];
    float* out = (float*)d_out;

    const int N  = in_sizes[0] / (R_ * D_);
    const int NR = N * R_;

    float* qbuf = (float*)d_ws;                                  // NR*64 f32
    float4* bp4 = (float4*)(qbuf + (size_t)NR * 64);             // NR float4
    float2* bp2 = (float2*)(bp4 + NR);                           // NR float2
    unsigned short* kb16 = (unsigned short*)(bp2 + NR);          // NR*64 bf16
    unsigned short* vT16 = kb16 + (size_t)NR * 64;               // NR*64 bf16 (transposed)
    unsigned short* WTb  = vT16 + (size_t)NR * 64;               // 192*1024 bf16

    prep_kernel<<<dim3(48 + (NR + 255) / 256), dim3(NT), 0, stream>>>(
        Wq, Wk, Wv, boxes, WTb, bp4, bp2, NR);
    proj_kernel<<<dim3((NR / 16) * 3), dim3(NT), 0, stream>>>(
        feat, WTb, bq, bk, bv, qbuf, kb16, vT16);
    relation_kernel<<<dim3(NR), dim3(NT), 0, stream>>>(
        feat, geo_w, geo_b, qbuf, kb16, vT16, bp4, bp2, out);
}

// Round 6
// 56.340 us; speedup vs baseline: 12.3337x; 1.5479x over previous
//
#include <hip/hip_runtime.h>
#include <stdint.h>

#define R_ 512
#define D_ 1024
#define G_ 16
#define NT 256

typedef __attribute__((ext_vector_type(8))) short short8;
typedef __attribute__((ext_vector_type(4))) float floatx4;

__device__ __forceinline__ unsigned pk2bf(float a, float b) {
    unsigned ua = __builtin_bit_cast(unsigned, a) + 0x8000u;
    unsigned ub = __builtin_bit_cast(unsigned, b) + 0x8000u;
    return (ub & 0xFFFF0000u) | (ua >> 16);
}
__device__ __forceinline__ unsigned short f2bf(float a) {
    return (unsigned short)((__builtin_bit_cast(unsigned, a) + 0x8000u) >> 16);
}

// ---------- kernel 0: W transpose->bf16 + geo frag + box params ----------
__global__ __launch_bounds__(256) void prep_kernel(
    const float* __restrict__ Wq, const float* __restrict__ Wk,
    const float* __restrict__ Wv, const float* __restrict__ geo_w,
    const float* __restrict__ boxes,
    unsigned short* __restrict__ WTb, unsigned short* __restrict__ geoF,
    float4* __restrict__ bp4, float2* __restrict__ bp2, int NR)
{
    const int b = blockIdx.x, t = threadIdx.x;
    if (b < 48) {
        __shared__ float s[64][65];
        const int mat = b >> 4, rblk = b & 15;
        const float* Wsrc = (mat == 0) ? Wq : (mat == 1) ? Wk : Wv;
        const int d0 = rblk * 64;
        #pragma unroll
        for (int i = 0; i < 16; i++) {
            int e = t + i * 256;
            s[e >> 6][e & 63] = Wsrc[(size_t)(d0 + (e >> 6)) * 64 + (e & 63)];
        }
        __syncthreads();
        #pragma unroll
        for (int i = 0; i < 16; i++) {
            int e = t + i * 256;
            int c = e >> 6, r = e & 63;
            WTb[(size_t)(mat * 64 + c) * 1024 + d0 + r] = f2bf(s[r][c]);
        }
    } else if (b == 48) {
        #pragma unroll
        for (int i = 0; i < 4; i++) {
            int idx = t * 4 + i;
            int h = idx >> 9, rem = idx & 511, ll = rem >> 3, j = rem & 7;
            int e = h * 32 + (ll >> 4) * 8 + j, cc = ll & 15;
            geoF[idx] = f2bf(geo_w[e * G_ + cc]);
        }
    } else {
        int r = (b - 49) * 256 + t;
        if (r < NR) {
            float ymin = boxes[r*4+0], xmin = boxes[r*4+1];
            float ymax = boxes[r*4+2], xmax = boxes[r*4+3];
            float h = ymax - ymin + 1.0f, w = xmax - xmin + 1.0f;
            bp4[r] = make_float4(0.5f * (ymin + ymax), 0.5f * (xmin + xmax),
                                 __logf(h), __logf(w));
            bp2[r] = make_float2(1.0f / h, 1.0f / w);
        }
    }
}

// ---------- kernel 1: QKV projection via MFMA ----------
__global__ __launch_bounds__(256) void proj_kernel(
    const float* __restrict__ feat, const unsigned short* __restrict__ WTb,
    const float* __restrict__ bq, const float* __restrict__ bk,
    const float* __restrict__ bv,
    unsigned short* __restrict__ qd16, unsigned short* __restrict__ kb16,
    unsigned short* __restrict__ vT16)
{
    __shared__ __align__(16) unsigned short s_A[16][1032];

    const int t = threadIdx.x, l = t & 63, w = t >> 6;
    const int mb = blockIdx.x / 3, ng = blockIdx.x % 3;
    const long row0 = (long)mb * 16;

    const float4* f4 = (const float4*)(feat + row0 * D_);
    #pragma unroll
    for (int i = 0; i < 16; i++) {
        int e = t + i * 256;
        int row = e >> 8, c4 = e & 255;
        float4 v = f4[e];
        uint2 pk;
        pk.x = pk2bf(v.x, v.y);
        pk.y = pk2bf(v.z, v.w);
        *(uint2*)&s_A[row][c4 * 4] = pk;
    }
    __syncthreads();

    const int lc = l & 15, q = l >> 4;
    const int gcol = (ng * 4 + w) * 16 + lc;       // 0..191
    const unsigned short* bptr = WTb + (size_t)gcol * 1024 + q * 8;

    floatx4 acc = {0.f, 0.f, 0.f, 0.f};
    #pragma unroll 8
    for (int k0 = 0; k0 < 1024; k0 += 32) {
        short8 a  = *(const short8*)&s_A[lc][k0 + q * 8];
        short8 bb = *(const short8*)(bptr + k0);
        acc = __builtin_amdgcn_mfma_f32_16x16x32_bf16(a, bb, acc, 0, 0, 0);
    }

    const int mat = gcol >> 6, mcol = gcol & 63;
    const float* B = (mat == 0) ? bq : (mat == 1) ? bk : bv;
    const float bias = B[mcol];
    #pragma unroll
    for (int r = 0; r < 4; r++) {
        long gr = row0 + q * 4 + r;
        float val = acc[r] + bias;
        if (mat == 0)      qd16[gr * 64 + mcol] = f2bf(0.5f * val);
        else if (mat == 1) kb16[gr * 64 + mcol] = f2bf(val);
        else               vT16[((size_t)((gr >> 9) * 64 + mcol)) * 512 + (gr & 511)] = f2bf(val);
    }
}

// ---------- kernel 2: fused relation, 2 q-rows per block ----------
__global__ __launch_bounds__(256, 3) void relation_kernel(
    const float* __restrict__ feat, const float* __restrict__ geo_b,
    const unsigned short* __restrict__ geoF, const unsigned short* __restrict__ qd16,
    const unsigned short* __restrict__ kb16, const unsigned short* __restrict__ vT16,
    const float4* __restrict__ bp4, const float2* __restrict__ bp2,
    float* __restrict__ out)
{
    __shared__ __align__(16) unsigned short s_p[2][16][520];
    __shared__ float s_redm[2][4][16];
    __shared__ float s_reds[2][4][16];

    const int t = threadIdx.x;
    const int l = t & 63;
    const int w = t >> 6;
    const int c = l & 15;
    const int quad = l >> 4;
    const int nqA = blockIdx.x * 2, nqB = nqA + 1;
    const int n = nqA >> 9;

    const float4 qbA = bp4[nqA], qbB = bp4[nqB];
    const float2 qiA = bp2[nqA], qiB = bp2[nqB];
    const float gbias = geo_b[c];

    short8 bgeo0 = *(const short8*)(geoF + l * 8);
    short8 bgeo1 = *(const short8*)(geoF + 512 + l * 8);

    const bool act = (quad == ((c >> 1) & 3));
    const int hsel = c >> 3, jhalf = c & 1;
    uint2 qvA = *(const uint2*)(qd16 + (size_t)nqA * 64 + c * 4);
    uint2 qvB = *(const uint2*)(qd16 + (size_t)nqB * 64 + c * 4);
    short qA[4] = {(short)(qvA.x & 0xFFFF), (short)(qvA.x >> 16),
                   (short)(qvA.y & 0xFFFF), (short)(qvA.y >> 16)};
    short qB[4] = {(short)(qvB.x & 0xFFFF), (short)(qvB.x >> 16),
                   (short)(qvB.y & 0xFFFF), (short)(qvB.y >> 16)};
    short8 bqfA0, bqfA1, bqfB0, bqfB1;
    #pragma unroll
    for (int j = 0; j < 8; j++) {
        bool on0 = act && (hsel == 0) && ((j >> 2) == jhalf);
        bool on1 = act && (hsel == 1) && ((j >> 2) == jhalf);
        bqfA0[j] = on0 ? qA[j & 3] : (short)0;
        bqfA1[j] = on1 ? qA[j & 3] : (short)0;
        bqfB0[j] = on0 ? qB[j & 3] : (short)0;
        bqfB1[j] = on1 ? qB[j & 3] : (short)0;
    }

    const float C8[8] = {
        15.91549431f,
        15.91549431f * 0.4216965034f,
        15.91549431f * 0.1778279410f,
        15.91549431f * 0.0749894209f,
        15.91549431f * 0.0316227766f,
        15.91549431f * 0.0133352143f,
        15.91549431f * 0.0056234133f,
        15.91549431f * 0.0023713737f };

    const float offs = (quad & 1) ? 0.25f : 0.0f;
    const bool qlow = (quad < 2);

    float logitA[8][4], logitB[8][4];
    const int krow0 = n * R_ + w * 128;

    #pragma unroll
    for (int ti = 0; ti < 8; ti++) {
        float4 kb = bp4[krow0 + ti * 16 + c];

        float aA  = qlow ? (qbA.x - kb.x) * qiA.x : (qbA.y - kb.y) * qiA.y;
        float pAa = __logf(fmaxf(aA, 1e-5f));
        float pAb = qlow ? (qbA.z - kb.z) : (qbA.w - kb.w);
        float aB  = qlow ? (qbB.x - kb.x) * qiB.x : (qbB.y - kb.y) * qiB.y;
        float pBa = __logf(fmaxf(aB, 1e-5f));
        float pBb = qlow ? (qbB.z - kb.z) : (qbB.w - kb.w);

        short8 aeA0, aeA1, aeB0, aeB1;
        #pragma unroll
        for (int j = 0; j < 8; j++) {
            float r;
            r = pAa * C8[j]; r = r - rintf(r) + offs;
            aeA0[j] = (short)f2bf(__builtin_amdgcn_sinf(r));
            r = pAb * C8[j]; r = r - rintf(r) + offs;
            aeA1[j] = (short)f2bf(__builtin_amdgcn_sinf(r));
            r = pBa * C8[j]; r = r - rintf(r) + offs;
            aeB0[j] = (short)f2bf(__builtin_amdgcn_sinf(r));
            r = pBb * C8[j]; r = r - rintf(r) + offs;
            aeB1[j] = (short)f2bf(__builtin_amdgcn_sinf(r));
        }

        const unsigned short* kr = kb16 + (size_t)(krow0 + ti * 16 + c) * 64;
        short8 ak0 = *(const short8*)(kr + quad * 8);
        short8 ak1 = *(const short8*)(kr + 32 + quad * 8);

        floatx4 accgA = {0,0,0,0}, acckA = {0,0,0,0};
        floatx4 accgB = {0,0,0,0}, acckB = {0,0,0,0};
        accgA = __builtin_amdgcn_mfma_f32_16x16x32_bf16(aeA0, bgeo0, accgA, 0, 0, 0);
        accgA = __builtin_amdgcn_mfma_f32_16x16x32_bf16(aeA1, bgeo1, accgA, 0, 0, 0);
        accgB = __builtin_amdgcn_mfma_f32_16x16x32_bf16(aeB0, bgeo0, accgB, 0, 0, 0);
        accgB = __builtin_amdgcn_mfma_f32_16x16x32_bf16(aeB1, bgeo1, accgB, 0, 0, 0);
        acckA = __builtin_amdgcn_mfma_f32_16x16x32_bf16(ak0, bqfA0, acckA, 0, 0, 0);
        acckA = __builtin_amdgcn_mfma_f32_16x16x32_bf16(ak1, bqfA1, acckA, 0, 0, 0);
        acckB = __builtin_amdgcn_mfma_f32_16x16x32_bf16(ak0, bqfB0, acckB, 0, 0, 0);
        acckB = __builtin_amdgcn_mfma_f32_16x16x32_bf16(ak1, bqfB1, acckB, 0, 0, 0);

        #pragma unroll
        for (int r = 0; r < 4; r++) {
            logitA[ti][r] = __logf(fmaxf(accgA[r] + gbias, 1e-6f)) + acckA[r];
            logitB[ti][r] = __logf(fmaxf(accgB[r] + gbias, 1e-6f)) + acckB[r];
        }
    }

    float mxA = -3.0e38f, mxB = -3.0e38f;
    #pragma unroll
    for (int ti = 0; ti < 8; ti++)
        #pragma unroll
        for (int r = 0; r < 4; r++) {
            mxA = fmaxf(mxA, logitA[ti][r]);
            mxB = fmaxf(mxB, logitB[ti][r]);
        }
    mxA = fmaxf(mxA, __shfl_xor(mxA, 16));
    mxA = fmaxf(mxA, __shfl_xor(mxA, 32));
    mxB = fmaxf(mxB, __shfl_xor(mxB, 16));
    mxB = fmaxf(mxB, __shfl_xor(mxB, 32));
    if (l < 16) { s_redm[0][w][l] = mxA; s_redm[1][w][l] = mxB; }
    __syncthreads();
    float mgA = fmaxf(fmaxf(s_redm[0][0][c], s_redm[0][1][c]),
                      fmaxf(s_redm[0][2][c], s_redm[0][3][c]));
    float mgB = fmaxf(fmaxf(s_redm[1][0][c], s_redm[1][1][c]),
                      fmaxf(s_redm[1][2][c], s_redm[1][3][c]));

    float sumA = 0.f, sumB = 0.f;
    #pragma unroll
    for (int ti = 0; ti < 8; ti++) {
        int k0 = w * 128 + ti * 16 + quad * 4;
        float eA0 = __expf(logitA[ti][0] - mgA);
        float eA1 = __expf(logitA[ti][1] - mgA);
        float eA2 = __expf(logitA[ti][2] - mgA);
        float eA3 = __expf(logitA[ti][3] - mgA);
        sumA += (eA0 + eA1) + (eA2 + eA3);
        uint2 pkA; pkA.x = pk2bf(eA0, eA1); pkA.y = pk2bf(eA2, eA3);
        *(uint2*)&s_p[0][c][k0] = pkA;
        float eB0 = __expf(logitB[ti][0] - mgB);
        float eB1 = __expf(logitB[ti][1] - mgB);
        float eB2 = __expf(logitB[ti][2] - mgB);
        float eB3 = __expf(logitB[ti][3] - mgB);
        sumB += (eB0 + eB1) + (eB2 + eB3);
        uint2 pkB; pkB.x = pk2bf(eB0, eB1); pkB.y = pk2bf(eB2, eB3);
        *(uint2*)&s_p[1][c][k0] = pkB;
    }
    sumA += __shfl_xor(sumA, 16);
    sumA += __shfl_xor(sumA, 32);
    sumB += __shfl_xor(sumB, 16);
    sumB += __shfl_xor(sumB, 32);
    if (l < 16) { s_reds[0][w][l] = sumA; s_reds[1][w][l] = sumB; }
    __syncthreads();

    floatx4 accpA = {0,0,0,0}, accpB = {0,0,0,0};
    const unsigned short* vrow = vT16 + ((size_t)(n * 64 + w * 16 + c)) * 512;
    #pragma unroll
    for (int ks = 0; ks < 16; ks++) {
        short8 bv8 = *(const short8*)(vrow + ks * 32 + quad * 8);
        short8 apA = *(const short8*)(&s_p[0][c][ks * 32 + quad * 8]);
        short8 apB = *(const short8*)(&s_p[1][c][ks * 32 + quad * 8]);
        accpA = __builtin_amdgcn_mfma_f32_16x16x32_bf16(apA, bv8, accpA, 0, 0, 0);
        accpB = __builtin_amdgcn_mfma_f32_16x16x32_bf16(apB, bv8, accpB, 0, 0, 0);
    }

    #pragma unroll
    for (int r = 0; r < 4; r++) {
        int gg = quad * 4 + r;
        float sA = (s_reds[0][0][gg] + s_reds[0][1][gg]) + (s_reds[0][2][gg] + s_reds[0][3][gg]);
        float sB = (s_reds[1][0][gg] + s_reds[1][1][gg]) + (s_reds[1][2][gg] + s_reds[1][3][gg]);
        size_t oA = (size_t)nqA * D_ + (size_t)gg * 64 + w * 16 + c;
        size_t oB = (size_t)nqB * D_ + (size_t)gg * 64 + w * 16 + c;
        out[oA] = feat[oA] + accpA[r] / sA;
        out[oB] = feat[oB] + accpB[r] / sB;
    }
}

extern "C" void kernel_launch(void* const* d_in, const int* in_sizes, int n_in,
                              void* d_out, int out_size, void* d_ws, size_t ws_size,
                              hipStream_t stream) {
    const float* feat  = (const float*)d_in[0];
    const float* boxes = (const float*)d_in[1];
    const float* geo_w = (const float*)d_in[2];
    const float* geo_b = (const float*)d_in[3];
    const float* Wq    = (const float*)d_in[4];
    const float* bq    = (const float*)d_in[5];
    const float* Wk    = (const float*)d_in[6];
    const float* bk    = (const float*)d_in[7];
    const float* Wv    = (const float*)d_in[8];
    const float* bv    = (const float*)d_in[9];
    float* out = (float*)d_out;

    const int N  = in_sizes[0] / (R_ * D_);
    const int NR = N * R_;

    float4* bp4 = (float4*)d_ws;
    float2* bp2 = (float2*)(bp4 + NR);
    unsigned short* kb16 = (unsigned short*)(bp2 + NR);
    unsigned short* vT16 = kb16 + (size_t)NR * 64;
    unsigned short* qd16 = vT16 + (size_t)NR * 64;
    unsigned short* WTb  = qd16 + (size_t)NR * 64;
    unsigned short* geoF = WTb + (size_t)192 * 1024;

    prep_kernel<<<dim3(49 + (NR + 255) / 256), dim3(NT), 0, stream>>>(
        Wq, Wk, Wv, geo_w, boxes, WTb, geoF, bp4, bp2, NR);
    proj_kernel<<<dim3((NR / 16) * 3), dim3(NT), 0, stream>>>(
        feat, WTb, bq, bk, bv, qd16, kb16, vT16);
    relation_kernel<<<dim3(NR / 2), dim3(NT), 0, stream>>>(
        feat, geo_b, geoF, qd16, kb16, vT16, bp4, bp2, out);
}

// Round 7
// 50.898 us; speedup vs baseline: 13.6526x; 1.1069x over previous
//
#include <hip/hip_runtime.h>
#include <stdint.h>

#define R_ 512
#define D_ 1024
#define G_ 16
#define NT 256

typedef __attribute__((ext_vector_type(8))) short short8;
typedef __attribute__((ext_vector_type(4))) float floatx4;

__device__ __forceinline__ unsigned pk2bf(float a, float b) {
    unsigned ua = __builtin_bit_cast(unsigned, a) + 0x8000u;
    unsigned ub = __builtin_bit_cast(unsigned, b) + 0x8000u;
    return (ub & 0xFFFF0000u) | (ua >> 16);
}
__device__ __forceinline__ unsigned short f2bf(float a) {
    return (unsigned short)((__builtin_bit_cast(unsigned, a) + 0x8000u) >> 16);
}

// ---------- kernel 0: W transpose->bf16 + geo frag + box params ----------
__global__ __launch_bounds__(256) void prep_kernel(
    const float* __restrict__ Wq, const float* __restrict__ Wk,
    const float* __restrict__ Wv, const float* __restrict__ geo_w,
    const float* __restrict__ boxes,
    unsigned short* __restrict__ WTb, unsigned short* __restrict__ geoF,
    float4* __restrict__ bp4, float2* __restrict__ bp2, int NR)
{
    const int b = blockIdx.x, t = threadIdx.x;
    if (b < 48) {
        __shared__ float s[64][65];
        const int mat = b >> 4, rblk = b & 15;
        const float* Wsrc = (mat == 0) ? Wq : (mat == 1) ? Wk : Wv;
        const int d0 = rblk * 64;
        #pragma unroll
        for (int i = 0; i < 16; i++) {
            int e = t + i * 256;
            s[e >> 6][e & 63] = Wsrc[(size_t)(d0 + (e >> 6)) * 64 + (e & 63)];
        }
        __syncthreads();
        #pragma unroll
        for (int i = 0; i < 16; i++) {
            int e = t + i * 256;
            int c = e >> 6, r = e & 63;
            WTb[(size_t)(mat * 64 + c) * 1024 + d0 + r] = f2bf(s[r][c]);
        }
    } else if (b == 48) {
        #pragma unroll
        for (int i = 0; i < 4; i++) {
            int idx = t * 4 + i;
            int h = idx >> 9, rem = idx & 511, ll = rem >> 3, j = rem & 7;
            int e = h * 32 + (ll >> 4) * 8 + j, cc = ll & 15;
            geoF[idx] = f2bf(geo_w[e * G_ + cc]);
        }
    } else {
        int r = (b - 49) * 256 + t;
        if (r < NR) {
            float ymin = boxes[r*4+0], xmin = boxes[r*4+1];
            float ymax = boxes[r*4+2], xmax = boxes[r*4+3];
            float h = ymax - ymin + 1.0f, w = xmax - xmin + 1.0f;
            bp4[r] = make_float4(0.5f * (ymin + ymax), 0.5f * (xmin + xmax),
                                 __logf(h), __logf(w));
            bp2[r] = make_float2(1.0f / h, 1.0f / w);
        }
    }
}

// ---------- kernel 1: QKV projection via MFMA ----------
__global__ __launch_bounds__(256) void proj_kernel(
    const float* __restrict__ feat, const unsigned short* __restrict__ WTb,
    const float* __restrict__ bq, const float* __restrict__ bk,
    const float* __restrict__ bv,
    unsigned short* __restrict__ qd16, unsigned short* __restrict__ kb16,
    unsigned short* __restrict__ vT16)
{
    __shared__ __align__(16) unsigned short s_A[16][1032];

    const int t = threadIdx.x, l = t & 63, w = t >> 6;
    const int mb = blockIdx.x / 3, ng = blockIdx.x % 3;
    const long row0 = (long)mb * 16;

    const float4* f4 = (const float4*)(feat + row0 * D_);
    #pragma unroll
    for (int i = 0; i < 16; i++) {
        int e = t + i * 256;
        int row = e >> 8, c4 = e & 255;
        float4 v = f4[e];
        uint2 pk;
        pk.x = pk2bf(v.x, v.y);
        pk.y = pk2bf(v.z, v.w);
        *(uint2*)&s_A[row][c4 * 4] = pk;
    }
    __syncthreads();

    const int lc = l & 15, q = l >> 4;
    const int gcol = (ng * 4 + w) * 16 + lc;       // 0..191
    const unsigned short* bptr = WTb + (size_t)gcol * 1024 + q * 8;

    floatx4 acc = {0.f, 0.f, 0.f, 0.f};
    #pragma unroll 8
    for (int k0 = 0; k0 < 1024; k0 += 32) {
        short8 a  = *(const short8*)&s_A[lc][k0 + q * 8];
        short8 bb = *(const short8*)(bptr + k0);
        acc = __builtin_amdgcn_mfma_f32_16x16x32_bf16(a, bb, acc, 0, 0, 0);
    }

    const int mat = gcol >> 6, mcol = gcol & 63;
    const float* B = (mat == 0) ? bq : (mat == 1) ? bk : bv;
    const float bias = B[mcol];
    #pragma unroll
    for (int r = 0; r < 4; r++) {
        long gr = row0 + q * 4 + r;
        float val = acc[r] + bias;
        if (mat == 0)      qd16[gr * 64 + mcol] = f2bf(0.5f * val);
        else if (mat == 1) kb16[gr * 64 + mcol] = f2bf(val);
        else               vT16[((size_t)((gr >> 9) * 64 + mcol)) * 512 + (gr & 511)] = f2bf(val);
    }
}

// ---------- kernel 2: fused relation, 2 q-rows per block, single-pass softmax ----------
__global__ __launch_bounds__(256, 4) void relation_kernel(
    const float* __restrict__ feat, const float* __restrict__ geo_b,
    const unsigned short* __restrict__ geoF, const unsigned short* __restrict__ qd16,
    const unsigned short* __restrict__ kb16, const unsigned short* __restrict__ vT16,
    const float4* __restrict__ bp4, const float2* __restrict__ bp2,
    float* __restrict__ out)
{
    __shared__ __align__(16) unsigned short s_p[2][16][520];
    __shared__ float s_reds[2][4][16];

    const int t = threadIdx.x;
    const int l = t & 63;
    const int w = t >> 6;
    const int c = l & 15;
    const int quad = l >> 4;
    const int nqA = blockIdx.x * 2, nqB = nqA + 1;
    const int n = nqA >> 9;

    const float4 qbA = bp4[nqA], qbB = bp4[nqB];
    const float2 qiA = bp2[nqA], qiB = bp2[nqB];
    const float gbias = geo_b[c];

    short8 bgeo0 = *(const short8*)(geoF + l * 8);
    short8 bgeo1 = *(const short8*)(geoF + 512 + l * 8);

    const bool act = (quad == ((c >> 1) & 3));
    const int hsel = c >> 3, jhalf = c & 1;
    uint2 qvA = *(const uint2*)(qd16 + (size_t)nqA * 64 + c * 4);
    uint2 qvB = *(const uint2*)(qd16 + (size_t)nqB * 64 + c * 4);
    short qA[4] = {(short)(qvA.x & 0xFFFF), (short)(qvA.x >> 16),
                   (short)(qvA.y & 0xFFFF), (short)(qvA.y >> 16)};
    short qB[4] = {(short)(qvB.x & 0xFFFF), (short)(qvB.x >> 16),
                   (short)(qvB.y & 0xFFFF), (short)(qvB.y >> 16)};
    short8 bqfA0, bqfA1, bqfB0, bqfB1;
    #pragma unroll
    for (int j = 0; j < 8; j++) {
        bool on0 = act && (hsel == 0) && ((j >> 2) == jhalf);
        bool on1 = act && (hsel == 1) && ((j >> 2) == jhalf);
        bqfA0[j] = on0 ? qA[j & 3] : (short)0;
        bqfA1[j] = on1 ? qA[j & 3] : (short)0;
        bqfB0[j] = on0 ? qB[j & 3] : (short)0;
        bqfB1[j] = on1 ? qB[j & 3] : (short)0;
    }

    const float C8[8] = {
        15.91549431f,
        15.91549431f * 0.4216965034f,
        15.91549431f * 0.1778279410f,
        15.91549431f * 0.0749894209f,
        15.91549431f * 0.0316227766f,
        15.91549431f * 0.0133352143f,
        15.91549431f * 0.0056234133f,
        15.91549431f * 0.0023713737f };

    const float offs = (quad & 1) ? 0.25f : 0.0f;
    const bool qlow = (quad < 2);

    float sumA = 0.f, sumB = 0.f;
    const int krow0 = n * R_ + w * 128;

    #pragma unroll
    for (int ti = 0; ti < 8; ti++) {
        float4 kb = bp4[krow0 + ti * 16 + c];

        float aA  = qlow ? (qbA.x - kb.x) * qiA.x : (qbA.y - kb.y) * qiA.y;
        float pAa = __logf(fmaxf(aA, 1e-5f));
        float pAb = qlow ? (qbA.z - kb.z) : (qbA.w - kb.w);
        float aB  = qlow ? (qbB.x - kb.x) * qiB.x : (qbB.y - kb.y) * qiB.y;
        float pBa = __logf(fmaxf(aB, 1e-5f));
        float pBb = qlow ? (qbB.z - kb.z) : (qbB.w - kb.w);

        short8 aeA0, aeA1, aeB0, aeB1;
        #pragma unroll
        for (int j = 0; j < 8; j++) {
            float r;
            r = pAa * C8[j]; r = r - rintf(r) + offs;
            aeA0[j] = (short)f2bf(__builtin_amdgcn_sinf(r));
            r = pAb * C8[j]; r = r - rintf(r) + offs;
            aeA1[j] = (short)f2bf(__builtin_amdgcn_sinf(r));
            r = pBa * C8[j]; r = r - rintf(r) + offs;
            aeB0[j] = (short)f2bf(__builtin_amdgcn_sinf(r));
            r = pBb * C8[j]; r = r - rintf(r) + offs;
            aeB1[j] = (short)f2bf(__builtin_amdgcn_sinf(r));
        }

        const unsigned short* kr = kb16 + (size_t)(krow0 + ti * 16 + c) * 64;
        short8 ak0 = *(const short8*)(kr + quad * 8);
        short8 ak1 = *(const short8*)(kr + 32 + quad * 8);

        floatx4 accgA = {0,0,0,0}, acckA = {0,0,0,0};
        floatx4 accgB = {0,0,0,0}, acckB = {0,0,0,0};
        accgA = __builtin_amdgcn_mfma_f32_16x16x32_bf16(aeA0, bgeo0, accgA, 0, 0, 0);
        accgA = __builtin_amdgcn_mfma_f32_16x16x32_bf16(aeA1, bgeo1, accgA, 0, 0, 0);
        accgB = __builtin_amdgcn_mfma_f32_16x16x32_bf16(aeB0, bgeo0, accgB, 0, 0, 0);
        accgB = __builtin_amdgcn_mfma_f32_16x16x32_bf16(aeB1, bgeo1, accgB, 0, 0, 0);
        acckA = __builtin_amdgcn_mfma_f32_16x16x32_bf16(ak0, bqfA0, acckA, 0, 0, 0);
        acckA = __builtin_amdgcn_mfma_f32_16x16x32_bf16(ak1, bqfA1, acckA, 0, 0, 0);
        acckB = __builtin_amdgcn_mfma_f32_16x16x32_bf16(ak0, bqfB0, acckB, 0, 0, 0);
        acckB = __builtin_amdgcn_mfma_f32_16x16x32_bf16(ak1, bqfB1, acckB, 0, 0, 0);

        // e = relu-clamped geometry weight * exp(appearance): exp(log(gw)+aw) = gw*exp(aw)
        int k0 = w * 128 + ti * 16 + quad * 4;
        float eA0 = fmaxf(accgA[0] + gbias, 1e-6f) * __expf(acckA[0]);
        float eA1 = fmaxf(accgA[1] + gbias, 1e-6f) * __expf(acckA[1]);
        float eA2 = fmaxf(accgA[2] + gbias, 1e-6f) * __expf(acckA[2]);
        float eA3 = fmaxf(accgA[3] + gbias, 1e-6f) * __expf(acckA[3]);
        sumA += (eA0 + eA1) + (eA2 + eA3);
        uint2 pkA; pkA.x = pk2bf(eA0, eA1); pkA.y = pk2bf(eA2, eA3);
        *(uint2*)&s_p[0][c][k0] = pkA;

        float eB0 = fmaxf(accgB[0] + gbias, 1e-6f) * __expf(acckB[0]);
        float eB1 = fmaxf(accgB[1] + gbias, 1e-6f) * __expf(acckB[1]);
        float eB2 = fmaxf(accgB[2] + gbias, 1e-6f) * __expf(acckB[2]);
        float eB3 = fmaxf(accgB[3] + gbias, 1e-6f) * __expf(acckB[3]);
        sumB += (eB0 + eB1) + (eB2 + eB3);
        uint2 pkB; pkB.x = pk2bf(eB0, eB1); pkB.y = pk2bf(eB2, eB3);
        *(uint2*)&s_p[1][c][k0] = pkB;
    }

    sumA += __shfl_xor(sumA, 16);
    sumA += __shfl_xor(sumA, 32);
    sumB += __shfl_xor(sumB, 16);
    sumB += __shfl_xor(sumB, 32);
    if (l < 16) { s_reds[0][w][l] = sumA; s_reds[1][w][l] = sumB; }
    __syncthreads();

    floatx4 accpA = {0,0,0,0}, accpB = {0,0,0,0};
    const unsigned short* vrow = vT16 + ((size_t)(n * 64 + w * 16 + c)) * 512;
    #pragma unroll
    for (int ks = 0; ks < 16; ks++) {
        short8 bv8 = *(const short8*)(vrow + ks * 32 + quad * 8);
        short8 apA = *(const short8*)(&s_p[0][c][ks * 32 + quad * 8]);
        short8 apB = *(const short8*)(&s_p[1][c][ks * 32 + quad * 8]);
        accpA = __builtin_amdgcn_mfma_f32_16x16x32_bf16(apA, bv8, accpA, 0, 0, 0);
        accpB = __builtin_amdgcn_mfma_f32_16x16x32_bf16(apB, bv8, accpB, 0, 0, 0);
    }

    #pragma unroll
    for (int r = 0; r < 4; r++) {
        int gg = quad * 4 + r;
        float sA = (s_reds[0][0][gg] + s_reds[0][1][gg]) + (s_reds[0][2][gg] + s_reds[0][3][gg]);
        float sB = (s_reds[1][0][gg] + s_reds[1][1][gg]) + (s_reds[1][2][gg] + s_reds[1][3][gg]);
        size_t oA = (size_t)nqA * D_ + (size_t)gg * 64 + w * 16 + c;
        size_t oB = (size_t)nqB * D_ + (size_t)gg * 64 + w * 16 + c;
        out[oA] = feat[oA] + accpA[r] / sA;
        out[oB] = feat[oB] + accpB[r] / sB;
    }
}

extern "C" void kernel_launch(void* const* d_in, const int* in_sizes, int n_in,
                              void* d_out, int out_size, void* d_ws, size_t ws_size,
                              hipStream_t stream) {
    const float* feat  = (const float*)d_in[0];
    const float* boxes = (const float*)d_in[1];
    const float* geo_w = (const float*)d_in[2];
    const float* geo_b = (const float*)d_in[3];
    const float* Wq    = (const float*)d_in[4];
    const float* bq    = (const float*)d_in[5];
    const float* Wk    = (const float*)d_in[6];
    const float* bk    = (const float*)d_in[7];
    const float* Wv    = (const float*)d_in[8];
    const float* bv    = (const float*)d_in[9];
    float* out = (float*)d_out;

    const int N  = in_sizes[0] / (R_ * D_);
    const int NR = N * R_;

    float4* bp4 = (float4*)d_ws;
    float2* bp2 = (float2*)(bp4 + NR);
    unsigned short* kb16 = (unsigned short*)(bp2 + NR);
    unsigned short* vT16 = kb16 + (size_t)NR * 64;
    unsigned short* qd16 = vT16 + (size_t)NR * 64;
    unsigned short* WTb  = qd16 + (size_t)NR * 64;
    unsigned short* geoF = WTb + (size_t)192 * 1024;

    prep_kernel<<<dim3(49 + (NR + 255) / 256), dim3(NT), 0, stream>>>(
        Wq, Wk, Wv, geo_w, boxes, WTb, geoF, bp4, bp2, NR);
    proj_kernel<<<dim3((NR / 16) * 3), dim3(NT), 0, stream>>>(
        feat, WTb, bq, bk, bv, qd16, kb16, vT16);
    relation_kernel<<<dim3(NR / 2), dim3(NT), 0, stream>>>(
        feat, geo_b, geoF, qd16, kb16, vT16, bp4, bp2, out);
}

// Round 8
// 48.711 us; speedup vs baseline: 14.2655x; 1.0449x over previous
//
#include <hip/hip_runtime.h>
#include <stdint.h>

#define R_ 512
#define D_ 1024
#define G_ 16
#define NT 256

typedef __attribute__((ext_vector_type(8))) short short8;
typedef __attribute__((ext_vector_type(4))) float floatx4;

#if __has_builtin(__builtin_amdgcn_fractf)
#define FRACT(x) __builtin_amdgcn_fractf(x)
#else
#define FRACT(x) ((x) - floorf(x))
#endif

__device__ __forceinline__ unsigned pk2bf(float a, float b) {
    unsigned ua = __builtin_bit_cast(unsigned, a) + 0x8000u;
    unsigned ub = __builtin_bit_cast(unsigned, b) + 0x8000u;
    return (ub & 0xFFFF0000u) | (ua >> 16);
}
__device__ __forceinline__ unsigned short f2bf(float a) {
    return (unsigned short)((__builtin_bit_cast(unsigned, a) + 0x8000u) >> 16);
}

// ---------- kernel 0: W transpose->bf16 + geo frag + box params ----------
__global__ __launch_bounds__(256) void prep_kernel(
    const float* __restrict__ Wq, const float* __restrict__ Wk,
    const float* __restrict__ Wv, const float* __restrict__ geo_w,
    const float* __restrict__ boxes,
    unsigned short* __restrict__ WTb, unsigned short* __restrict__ geoF,
    float4* __restrict__ bp4, float2* __restrict__ bp2, int NR)
{
    const int b = blockIdx.x, t = threadIdx.x;
    if (b < 48) {
        __shared__ float s[64][65];
        const int mat = b >> 4, rblk = b & 15;
        const float* Wsrc = (mat == 0) ? Wq : (mat == 1) ? Wk : Wv;
        const int d0 = rblk * 64;
        #pragma unroll
        for (int i = 0; i < 16; i++) {
            int e = t + i * 256;
            s[e >> 6][e & 63] = Wsrc[(size_t)(d0 + (e >> 6)) * 64 + (e & 63)];
        }
        __syncthreads();
        #pragma unroll
        for (int i = 0; i < 16; i++) {
            int e = t + i * 256;
            int c = e >> 6, r = e & 63;
            WTb[(size_t)(mat * 64 + c) * 1024 + d0 + r] = f2bf(s[r][c]);
        }
    } else if (b == 48) {
        #pragma unroll
        for (int i = 0; i < 4; i++) {
            int idx = t * 4 + i;
            int h = idx >> 9, rem = idx & 511, ll = rem >> 3, j = rem & 7;
            int e = h * 32 + (ll >> 4) * 8 + j, cc = ll & 15;
            geoF[idx] = f2bf(geo_w[e * G_ + cc]);
        }
    } else {
        int r = (b - 49) * 256 + t;
        if (r < NR) {
            float ymin = boxes[r*4+0], xmin = boxes[r*4+1];
            float ymax = boxes[r*4+2], xmax = boxes[r*4+3];
            float h = ymax - ymin + 1.0f, w = xmax - xmin + 1.0f;
            bp4[r] = make_float4(0.5f * (ymin + ymax), 0.5f * (xmin + xmax),
                                 __logf(h), __logf(w));
            bp2[r] = make_float2(1.0f / h, 1.0f / w);
        }
    }
}

// ---------- kernel 1: QKV projection via MFMA ----------
__global__ __launch_bounds__(256) void proj_kernel(
    const float* __restrict__ feat, const unsigned short* __restrict__ WTb,
    const float* __restrict__ bq, const float* __restrict__ bk,
    const float* __restrict__ bv,
    unsigned short* __restrict__ qd16, unsigned short* __restrict__ kb16,
    unsigned short* __restrict__ vT16)
{
    __shared__ __align__(16) unsigned short s_A[16][1032];

    const int t = threadIdx.x, l = t & 63, w = t >> 6;
    const int mb = blockIdx.x / 3, ng = blockIdx.x % 3;
    const long row0 = (long)mb * 16;

    const float4* f4 = (const float4*)(feat + row0 * D_);
    #pragma unroll
    for (int i = 0; i < 16; i++) {
        int e = t + i * 256;
        int row = e >> 8, c4 = e & 255;
        float4 v = f4[e];
        uint2 pk;
        pk.x = pk2bf(v.x, v.y);
        pk.y = pk2bf(v.z, v.w);
        *(uint2*)&s_A[row][c4 * 4] = pk;
    }
    __syncthreads();

    const int lc = l & 15, q = l >> 4;
    const int gcol = (ng * 4 + w) * 16 + lc;       // 0..191
    const unsigned short* bptr = WTb + (size_t)gcol * 1024 + q * 8;

    floatx4 acc = {0.f, 0.f, 0.f, 0.f};
    #pragma unroll 8
    for (int k0 = 0; k0 < 1024; k0 += 32) {
        short8 a  = *(const short8*)&s_A[lc][k0 + q * 8];
        short8 bb = *(const short8*)(bptr + k0);
        acc = __builtin_amdgcn_mfma_f32_16x16x32_bf16(a, bb, acc, 0, 0, 0);
    }

    const int mat = gcol >> 6, mcol = gcol & 63;
    const float* B = (mat == 0) ? bq : (mat == 1) ? bk : bv;
    const float bias = B[mcol];
    #pragma unroll
    for (int r = 0; r < 4; r++) {
        long gr = row0 + q * 4 + r;
        float val = acc[r] + bias;
        if (mat == 0)      qd16[gr * 64 + mcol] = f2bf(0.5f * val);
        else if (mat == 1) kb16[gr * 64 + mcol] = f2bf(val);
        else               vT16[((size_t)((gr >> 9) * 64 + mcol)) * 512 + (gr & 511)] = f2bf(val);
    }
}

// ---------- kernel 2: fused relation, 2 q-rows per block, single-pass softmax ----------
__global__ __launch_bounds__(256, 4) void relation_kernel(
    const float* __restrict__ feat, const float* __restrict__ geo_b,
    const unsigned short* __restrict__ geoF, const unsigned short* __restrict__ qd16,
    const unsigned short* __restrict__ kb16, const unsigned short* __restrict__ vT16,
    const float4* __restrict__ bp4, const float2* __restrict__ bp2,
    float* __restrict__ out)
{
    __shared__ __align__(16) unsigned short s_p[2][16][520];
    __shared__ float s_reds[2][4][16];

    const int t = threadIdx.x;
    const int l = t & 63;
    const int w = t >> 6;
    const int c = l & 15;
    const int quad = l >> 4;
    const int nqA = blockIdx.x * 2, nqB = nqA + 1;
    const int n = nqA >> 9;

    const float4 qbA = bp4[nqA], qbB = bp4[nqB];
    const float2 qiA = bp2[nqA], qiB = bp2[nqB];
    const float gbias = geo_b[c];

    short8 bgeo0 = *(const short8*)(geoF + l * 8);
    short8 bgeo1 = *(const short8*)(geoF + 512 + l * 8);

    const bool act = (quad == ((c >> 1) & 3));
    const int hsel = c >> 3, jhalf = c & 1;
    uint2 qvA = *(const uint2*)(qd16 + (size_t)nqA * 64 + c * 4);
    uint2 qvB = *(const uint2*)(qd16 + (size_t)nqB * 64 + c * 4);
    short qA[4] = {(short)(qvA.x & 0xFFFF), (short)(qvA.x >> 16),
                   (short)(qvA.y & 0xFFFF), (short)(qvA.y >> 16)};
    short qB[4] = {(short)(qvB.x & 0xFFFF), (short)(qvB.x >> 16),
                   (short)(qvB.y & 0xFFFF), (short)(qvB.y >> 16)};
    short8 bqfA0, bqfA1, bqfB0, bqfB1;
    #pragma unroll
    for (int j = 0; j < 8; j++) {
        bool on0 = act && (hsel == 0) && ((j >> 2) == jhalf);
        bool on1 = act && (hsel == 1) && ((j >> 2) == jhalf);
        bqfA0[j] = on0 ? qA[j & 3] : (short)0;
        bqfA1[j] = on1 ? qA[j & 3] : (short)0;
        bqfB0[j] = on0 ? qB[j & 3] : (short)0;
        bqfB1[j] = on1 ? qB[j & 3] : (short)0;
    }

    const float C8[8] = {
        15.91549431f,
        15.91549431f * 0.4216965034f,
        15.91549431f * 0.1778279410f,
        15.91549431f * 0.0749894209f,
        15.91549431f * 0.0316227766f,
        15.91549431f * 0.0133352143f,
        15.91549431f * 0.0056234133f,
        15.91549431f * 0.0023713737f };

    const float offs = (quad & 1) ? 0.25f : 0.0f;   // cos(2πx) = sin(2π·fract(x+0.25))
    const bool qlow = (quad < 2);

    float sumA = 0.f, sumB = 0.f;
    const int krow0 = n * R_ + w * 128;

    #pragma unroll
    for (int ti = 0; ti < 8; ti++) {
        float4 kb = bp4[krow0 + ti * 16 + c];

        float aA  = qlow ? (qbA.x - kb.x) * qiA.x : (qbA.y - kb.y) * qiA.y;
        float pAa = __logf(fmaxf(aA, 1e-5f));
        float pAb = qlow ? (qbA.z - kb.z) : (qbA.w - kb.w);
        float aB  = qlow ? (qbB.x - kb.x) * qiB.x : (qbB.y - kb.y) * qiB.y;
        float pBa = __logf(fmaxf(aB, 1e-5f));
        float pBb = qlow ? (qbB.z - kb.z) : (qbB.w - kb.w);

        uint4 uA0, uA1, uB0, uB1;
        #pragma unroll
        for (int jj = 0; jj < 4; jj++) {
            float r0, r1;
            r0 = FRACT(fmaf(pAa, C8[2*jj],   offs));
            r1 = FRACT(fmaf(pAa, C8[2*jj+1], offs));
            (&uA0.x)[jj] = pk2bf(__builtin_amdgcn_sinf(r0), __builtin_amdgcn_sinf(r1));
            r0 = FRACT(fmaf(pAb, C8[2*jj],   offs));
            r1 = FRACT(fmaf(pAb, C8[2*jj+1], offs));
            (&uA1.x)[jj] = pk2bf(__builtin_amdgcn_sinf(r0), __builtin_amdgcn_sinf(r1));
            r0 = FRACT(fmaf(pBa, C8[2*jj],   offs));
            r1 = FRACT(fmaf(pBa, C8[2*jj+1], offs));
            (&uB0.x)[jj] = pk2bf(__builtin_amdgcn_sinf(r0), __builtin_amdgcn_sinf(r1));
            r0 = FRACT(fmaf(pBb, C8[2*jj],   offs));
            r1 = FRACT(fmaf(pBb, C8[2*jj+1], offs));
            (&uB1.x)[jj] = pk2bf(__builtin_amdgcn_sinf(r0), __builtin_amdgcn_sinf(r1));
        }
        short8 aeA0 = __builtin_bit_cast(short8, uA0);
        short8 aeA1 = __builtin_bit_cast(short8, uA1);
        short8 aeB0 = __builtin_bit_cast(short8, uB0);
        short8 aeB1 = __builtin_bit_cast(short8, uB1);

        const unsigned short* kr = kb16 + (size_t)(krow0 + ti * 16 + c) * 64;
        short8 ak0 = *(const short8*)(kr + quad * 8);
        short8 ak1 = *(const short8*)(kr + 32 + quad * 8);

        floatx4 accgA = {0,0,0,0}, acckA = {0,0,0,0};
        floatx4 accgB = {0,0,0,0}, acckB = {0,0,0,0};
        accgA = __builtin_amdgcn_mfma_f32_16x16x32_bf16(aeA0, bgeo0, accgA, 0, 0, 0);
        accgA = __builtin_amdgcn_mfma_f32_16x16x32_bf16(aeA1, bgeo1, accgA, 0, 0, 0);
        accgB = __builtin_amdgcn_mfma_f32_16x16x32_bf16(aeB0, bgeo0, accgB, 0, 0, 0);
        accgB = __builtin_amdgcn_mfma_f32_16x16x32_bf16(aeB1, bgeo1, accgB, 0, 0, 0);
        acckA = __builtin_amdgcn_mfma_f32_16x16x32_bf16(ak0, bqfA0, acckA, 0, 0, 0);
        acckA = __builtin_amdgcn_mfma_f32_16x16x32_bf16(ak1, bqfA1, acckA, 0, 0, 0);
        acckB = __builtin_amdgcn_mfma_f32_16x16x32_bf16(ak0, bqfB0, acckB, 0, 0, 0);
        acckB = __builtin_amdgcn_mfma_f32_16x16x32_bf16(ak1, bqfB1, acckB, 0, 0, 0);

        int k0 = w * 128 + ti * 16 + quad * 4;
        float eA0 = fmaxf(accgA[0] + gbias, 1e-6f) * __expf(acckA[0]);
        float eA1 = fmaxf(accgA[1] + gbias, 1e-6f) * __expf(acckA[1]);
        float eA2 = fmaxf(accgA[2] + gbias, 1e-6f) * __expf(acckA[2]);
        float eA3 = fmaxf(accgA[3] + gbias, 1e-6f) * __expf(acckA[3]);
        sumA += (eA0 + eA1) + (eA2 + eA3);
        uint2 pkA; pkA.x = pk2bf(eA0, eA1); pkA.y = pk2bf(eA2, eA3);
        *(uint2*)&s_p[0][c][k0] = pkA;

        float eB0 = fmaxf(accgB[0] + gbias, 1e-6f) * __expf(acckB[0]);
        float eB1 = fmaxf(accgB[1] + gbias, 1e-6f) * __expf(acckB[1]);
        float eB2 = fmaxf(accgB[2] + gbias, 1e-6f) * __expf(acckB[2]);
        float eB3 = fmaxf(accgB[3] + gbias, 1e-6f) * __expf(acckB[3]);
        sumB += (eB0 + eB1) + (eB2 + eB3);
        uint2 pkB; pkB.x = pk2bf(eB0, eB1); pkB.y = pk2bf(eB2, eB3);
        *(uint2*)&s_p[1][c][k0] = pkB;
    }

    sumA += __shfl_xor(sumA, 16);
    sumA += __shfl_xor(sumA, 32);
    sumB += __shfl_xor(sumB, 16);
    sumB += __shfl_xor(sumB, 32);
    if (l < 16) { s_reds[0][w][l] = sumA; s_reds[1][w][l] = sumB; }
    __syncthreads();

    floatx4 accpA = {0,0,0,0}, accpB = {0,0,0,0};
    const unsigned short* vrow = vT16 + ((size_t)(n * 64 + w * 16 + c)) * 512;
    #pragma unroll
    for (int ks = 0; ks < 16; ks++) {
        short8 bv8 = *(const short8*)(vrow + ks * 32 + quad * 8);
        short8 apA = *(const short8*)(&s_p[0][c][ks * 32 + quad * 8]);
        short8 apB = *(const short8*)(&s_p[1][c][ks * 32 + quad * 8]);
        accpA = __builtin_amdgcn_mfma_f32_16x16x32_bf16(apA, bv8, accpA, 0, 0, 0);
        accpB = __builtin_amdgcn_mfma_f32_16x16x32_bf16(apB, bv8, accpB, 0, 0, 0);
    }

    #pragma unroll
    for (int r = 0; r < 4; r++) {
        int gg = quad * 4 + r;
        float sA = (s_reds[0][0][gg] + s_reds[0][1][gg]) + (s_reds[0][2][gg] + s_reds[0][3][gg]);
        float sB = (s_reds[1][0][gg] + s_reds[1][1][gg]) + (s_reds[1][2][gg] + s_reds[1][3][gg]);
        size_t oA = (size_t)nqA * D_ + (size_t)gg * 64 + w * 16 + c;
        size_t oB = (size_t)nqB * D_ + (size_t)gg * 64 + w * 16 + c;
        out[oA] = feat[oA] + accpA[r] / sA;
        out[oB] = feat[oB] + accpB[r] / sB;
    }
}

extern "C" void kernel_launch(void* const* d_in, const int* in_sizes, int n_in,
                              void* d_out, int out_size, void* d_ws, size_t ws_size,
                              hipStream_t stream) {
    const float* feat  = (const float*)d_in[0];
    const float* boxes = (const float*)d_in[1];
    const float* geo_w = (const float*)d_in[2];
    const float* geo_b = (const float*)d_in[3];
    const float* Wq    = (const float*)d_in[4];
    const float* bq    = (const float*)d_in[5];
    const float* Wk    = (const float*)d_in[6];
    const float* bk    = (const float*)d_in[7];
    const float* Wv    = (const float*)d_in[8];
    const float* bv    = (const float*)d_in[9];
    float* out = (float*)d_out;

    const int N  = in_sizes[0] / (R_ * D_);
    const int NR = N * R_;

    float4* bp4 = (float4*)d_ws;
    float2* bp2 = (float2*)(bp4 + NR);
    unsigned short* kb16 = (unsigned short*)(bp2 + NR);
    unsigned short* vT16 = kb16 + (size_t)NR * 64;
    unsigned short* qd16 = vT16 + (size_t)NR * 64;
    unsigned short* WTb  = qd16 + (size_t)NR * 64;
    unsigned short* geoF = WTb + (size_t)192 * 1024;

    prep_kernel<<<dim3(49 + (NR + 255) / 256), dim3(NT), 0, stream>>>(
        Wq, Wk, Wv, geo_w, boxes, WTb, geoF, bp4, bp2, NR);
    proj_kernel<<<dim3((NR / 16) * 3), dim3(NT), 0, stream>>>(
        feat, WTb, bq, bk, bv, qd16, kb16, vT16);
    relation_kernel<<<dim3(NR / 2), dim3(NT), 0, stream>>>(
        feat, geo_b, geoF, qd16, kb16, vT16, bp4, bp2, out);
}